// Round 3
// baseline (1812.761 us; speedup 1.0000x reference)
//
#include <hip/hip_runtime.h>
#include <hip/hip_bf16.h>

typedef __hip_bfloat16 bf16;

#define N_ATOMS 25000
#define NE      800000
#define NEA     300000
#define NT      1600000

// ------------------------------------------------------------------
// CSR build: histogram
// ------------------------------------------------------------------
__global__ void k_count(const int* __restrict__ esrc, const int* __restrict__ cat,
                        int* __restrict__ ecnt, int* __restrict__ tcnt) {
    int i = blockIdx.x * blockDim.x + threadIdx.x;
    if (i < NE) {
        atomicAdd(&ecnt[esrc[i]], 1);
    } else {
        int j = i - NE;
        if (j < NT) atomicAdd(&tcnt[cat[j]], 1);
    }
}

// 2 blocks: block 0 scans edge counts, block 1 scans triplet counts
__global__ __launch_bounds__(1024) void k_scan(const int* cnt0, int* off0, int* cur0,
                                               const int* cnt1, int* off1, int* cur1,
                                               int n) {
    const int* cnt = blockIdx.x ? cnt1 : cnt0;
    int* off = blockIdx.x ? off1 : off0;
    int* cur = blockIdx.x ? cur1 : cur0;
    __shared__ int sh[1024];
    int carry = 0;
    for (int base = 0; base < n; base += 1024) {
        int i = base + (int)threadIdx.x;
        int v = (i < n) ? cnt[i] : 0;
        sh[threadIdx.x] = v;
        __syncthreads();
        for (int d = 1; d < 1024; d <<= 1) {
            int add = (threadIdx.x >= (unsigned)d) ? sh[threadIdx.x - d] : 0;
            __syncthreads();
            sh[threadIdx.x] += add;
            __syncthreads();
        }
        int incl = sh[threadIdx.x];
        int excl = incl - v + carry;
        if (i < n) { off[i] = excl; cur[i] = excl; }
        carry += sh[1023];
        __syncthreads();
    }
    if (threadIdx.x == 0) off[n] = carry;
}

__global__ void k_fill(const int* __restrict__ esrc, const int* __restrict__ cat,
                       int* __restrict__ ecur, int* __restrict__ eidx,
                       int* __restrict__ tcur, int* __restrict__ tidx) {
    int i = blockIdx.x * blockDim.x + threadIdx.x;
    if (i < NE) {
        int p = atomicAdd(&ecur[esrc[i]], 1);
        eidx[p] = i;
    } else {
        int j = i - NE;
        if (j < NT) {
            int p = atomicAdd(&tcur[cat[j]], 1);
            tidx[p] = j;
        }
    }
}

// ------------------------------------------------------------------
// s = xi @ W_si   (layer 0: xi = species_table[species], K=16)
// ------------------------------------------------------------------
__global__ void k_s0(const int* __restrict__ sp, const float* __restrict__ table,
                     const float* __restrict__ W, float* __restrict__ sbuf) {
    int idx = blockIdx.x * blockDim.x + threadIdx.x;
    if (idx >= N_ATOMS * 96) return;
    int i = idx / 96;
    int c = idx - i * 96;
    int s = sp[i];
    float acc = 0.f;
#pragma unroll
    for (int k = 0; k < 16; k++)
        acc += table[s * 16 + k] * W[k * 96 + c];
    sbuf[idx] = acc;
}

// layer 1: xi is N x 256 fp32
__global__ __launch_bounds__(128) void k_s1(const float* __restrict__ xi,
                                            const float* __restrict__ W,
                                            float* __restrict__ sbuf) {
    int i = blockIdx.x;
    __shared__ float x[256];
    for (int k = threadIdx.x; k < 256; k += 128) x[k] = xi[i * 256 + k];
    __syncthreads();
    int c = threadIdx.x;
    if (c < 96) {
        float acc = 0.f;
#pragma unroll 8
        for (int k = 0; k < 256; k++)
            acc += x[k] * W[k * 96 + c];
        sbuf[i * 96 + c] = acc;
    }
}

// ------------------------------------------------------------------
// da = (bessel(dist_angle)*switch_angle) @ W_da   -> EA x 8 fp32
// ------------------------------------------------------------------
__global__ void k_da(const float* __restrict__ dist, const float* __restrict__ sw,
                     const float* __restrict__ W, float* __restrict__ da) {
    int e = blockIdx.x * blockDim.x + threadIdx.x;
    if (e >= NEA) return;
    float d = dist[e];
    float s = sw[e];
    float rb[8];
#pragma unroll
    for (int n = 0; n < 8; n++)
        rb[n] = 0.7559289460f * __sinf((n + 1) * 0.8975979010f * d) / d * s;
    float w[8];
#pragma unroll
    for (int c = 0; c < 8; c++) {
        float acc = 0.f;
#pragma unroll
        for (int n = 0; n < 8; n++) acc += rb[n] * W[n * 8 + c];
        w[c] = acc;
    }
#pragma unroll
    for (int c = 0; c < 8; c++) da[e * 8 + c] = w[c];
}

// ------------------------------------------------------------------
// mi[i, n*32+c] = sum_{e in edges(i)} rb[e][n] * sbuf_dst[edge_dst[e]][c]
// one block (256 thr) per atom, 4 edges per iteration, no atomics
// ------------------------------------------------------------------
__global__ __launch_bounds__(256) void k_mi(const int* __restrict__ eoff,
                                            const int* __restrict__ eidx,
                                            const int* __restrict__ edst,
                                            const float* __restrict__ dist,
                                            const float* __restrict__ sw,
                                            const float* __restrict__ sbuf,
                                            float* __restrict__ mi) {
    int i = blockIdx.x;
    int beg = eoff[i], end = eoff[i + 1];
    __shared__ float rb_l[4][8];
    __shared__ float sd_l[4][33];
    int t = threadIdx.x;
    int n = t >> 5, c = t & 31;
    float acc = 0.f;
    for (int base = beg; base < end; base += 4) {
        if (t < 32) {
            int j = t >> 3, nn = t & 7;
            float v = 0.f;
            int p = base + j;
            if (p < end) {
                int e = eidx[p];
                float d = dist[e];
                float s = sw[e];
                v = 0.6324555320f * __sinf((nn + 1) * 0.6283185307f * d) / d * s;
            }
            rb_l[j][nn] = v;
        } else if (t >= 64 && t < 192) {
            int j = (t - 64) >> 5, cc = (t - 64) & 31;
            int p = base + j;
            float v = 0.f;
            if (p < end) {
                int e = eidx[p];
                int di = edst[e];
                v = sbuf[di * 96 + 64 + cc];
            }
            sd_l[j][cc] = v;
        }
        __syncthreads();
#pragma unroll
        for (int j = 0; j < 4; j++) acc += rb_l[j][n] * sd_l[j][c];
        __syncthreads();
    }
    mi[i * 256 + t] = acc;
}

// ------------------------------------------------------------------
// ami[i, n*8+c] = sum_{tr in trip(i)} cos(n*theta[tr]) * da[asrc][c]*da[adst][c]
// one block (64 thr) per atom, 8 triplets per iteration
// ------------------------------------------------------------------
__global__ __launch_bounds__(64) void k_ami(const int* __restrict__ toff,
                                            const int* __restrict__ tidx,
                                            const int* __restrict__ asrc,
                                            const int* __restrict__ adst,
                                            const float* __restrict__ ang,
                                            const float* __restrict__ da,
                                            float* __restrict__ ami) {
    int i = blockIdx.x;
    int beg = toff[i], end = toff[i + 1];
    __shared__ float dij_l[8][9];
    __shared__ float xa_l[8][6];
    int t = threadIdx.x;
    int n = t >> 3, c = t & 7;
    float acc = 0.f;
    for (int base = beg; base < end; base += 8) {
        int j = t >> 3, k = t & 7;
        int p = base + j;
        float v = 0.f;
        float th = 0.f;
        if (p < end) {
            int tr = tidx[p];
            int ea = asrc[tr], eb = adst[tr];
            v = da[ea * 8 + k] * da[eb * 8 + k];
            th = ang[tr];
        }
        dij_l[j][k] = v;
        if (k < 5) xa_l[j][k] = __cosf((float)k * th);
        __syncthreads();
        if (t < 40) {
#pragma unroll
            for (int j2 = 0; j2 < 8; j2++) acc += xa_l[j2][n] * dij_l[j2][c];
        }
        __syncthreads();
    }
    if (t < 40) ami[i * 40 + t] = acc;
}

// ------------------------------------------------------------------
// mix: dxi = tssr2(ei @ W_mix + b);  layer0: xi = dxi ; layer1: out = xi + dxi
// ei = [xi (16|256), si 64, mi 256, ami 40]
// ------------------------------------------------------------------
template <int LAYER>
__global__ __launch_bounds__(256) void k_mix(const int* __restrict__ sp,
                                             const float* __restrict__ table,
                                             const float* __restrict__ xi,
                                             const float* __restrict__ sbuf,
                                             const float* __restrict__ mi,
                                             const float* __restrict__ ami,
                                             const float* __restrict__ W,
                                             const float* __restrict__ b,
                                             float* __restrict__ xi_out,
                                             float* __restrict__ out) {
    constexpr int X = (LAYER == 0) ? 16 : 256;
    constexpr int DIN = X + 64 + 256 + 40;
    int i = blockIdx.x;
    __shared__ float ei[DIN];
    int t = threadIdx.x;
    if (LAYER == 0) {
        if (t < 16) {
            int s = sp[i];
            ei[t] = table[s * 16 + t];
        }
    } else {
        ei[t] = xi[i * 256 + t];
    }
    if (t < 64) ei[X + t] = sbuf[i * 96 + t];
    ei[X + 64 + t] = mi[i * 256 + t];
    if (t < 40) ei[X + 320 + t] = ami[i * 40 + t];
    __syncthreads();
    float acc = 0.f;
#pragma unroll 8
    for (int k = 0; k < DIN; k++)
        acc += ei[k] * W[k * 256 + t];
    acc += b[t];
    float ax = fabsf(acc);
    float v = (ax <= 1.f) ? acc : copysignf(2.f * __builtin_sqrtf(ax) - 1.f, acc);
    if (LAYER == 0) {
        xi_out[i * 256 + t] = v;
    } else {
        out[i * 256 + t] = ei[t] + v;
    }
}

// ------------------------------------------------------------------
extern "C" void kernel_launch(void* const* d_in, const int* in_sizes, int n_in,
                              void* d_out, int out_size, void* d_ws, size_t ws_size,
                              hipStream_t stream) {
    const int*   species     = (const int*)d_in[0];
    const int*   edge_src    = (const int*)d_in[1];
    const int*   edge_dst    = (const int*)d_in[2];
    const float* distances   = (const float*)d_in[3];
    const float* sw          = (const float*)d_in[4];
    const float* angles      = (const float*)d_in[5];
    const int*   angle_src   = (const int*)d_in[6];
    const int*   angle_dst   = (const int*)d_in[7];
    const int*   central     = (const int*)d_in[8];
    const float* dist_a      = (const float*)d_in[9];
    const float* sw_a        = (const float*)d_in[10];
    const float* table       = (const float*)d_in[11];
    const float* W_si0       = (const float*)d_in[12];
    const float* W_si1       = (const float*)d_in[13];
    const float* W_da0       = (const float*)d_in[14];
    const float* W_da1       = (const float*)d_in[15];
    const float* W_mix0      = (const float*)d_in[16];
    const float* b_mix0      = (const float*)d_in[17];
    const float* W_mix1      = (const float*)d_in[18];
    const float* b_mix1      = (const float*)d_in[19];
    float* out = (float*)d_out;

    // workspace bump allocator (all 256B aligned)
    char* p = (char*)d_ws;
    auto alloc = [&](size_t bytes) {
        char* r = p;
        p += (bytes + 255) & ~(size_t)255;
        return (void*)r;
    };
    float* xi   = (float*)alloc((size_t)N_ATOMS * 256 * 4);
    float* sbuf = (float*)alloc((size_t)N_ATOMS * 96 * 4);
    float* mi   = (float*)alloc((size_t)N_ATOMS * 256 * 4);
    float* ami  = (float*)alloc((size_t)N_ATOMS * 40 * 4);
    float* da   = (float*)alloc((size_t)NEA * 8 * 4);
    int* ecnt = (int*)alloc((size_t)N_ATOMS * 4);
    int* eoff = (int*)alloc((size_t)(N_ATOMS + 1) * 4);
    int* ecur = (int*)alloc((size_t)N_ATOMS * 4);
    int* eidx = (int*)alloc((size_t)NE * 4);
    int* tcnt = (int*)alloc((size_t)N_ATOMS * 4);
    int* toff = (int*)alloc((size_t)(N_ATOMS + 1) * 4);
    int* tcur = (int*)alloc((size_t)N_ATOMS * 4);
    int* tidx = (int*)alloc((size_t)NT * 4);
    (void)ws_size;

    hipMemsetAsync(ecnt, 0, (size_t)N_ATOMS * 4, stream);
    hipMemsetAsync(tcnt, 0, (size_t)N_ATOMS * 4, stream);

    int nct = NE + NT;
    k_count<<<(nct + 255) / 256, 256, 0, stream>>>(edge_src, central, ecnt, tcnt);
    k_scan<<<2, 1024, 0, stream>>>(ecnt, eoff, ecur, tcnt, toff, tcur, N_ATOMS);
    k_fill<<<(nct + 255) / 256, 256, 0, stream>>>(edge_src, central, ecur, eidx, tcur, tidx);

    // ---- layer 0 ----
    k_s0<<<(N_ATOMS * 96 + 255) / 256, 256, 0, stream>>>(species, table, W_si0, sbuf);
    k_da<<<(NEA + 255) / 256, 256, 0, stream>>>(dist_a, sw_a, W_da0, da);
    k_mi<<<N_ATOMS, 256, 0, stream>>>(eoff, eidx, edge_dst, distances, sw, sbuf, mi);
    k_ami<<<N_ATOMS, 64, 0, stream>>>(toff, tidx, angle_src, angle_dst, angles, da, ami);
    k_mix<0><<<N_ATOMS, 256, 0, stream>>>(species, table, nullptr, sbuf, mi, ami,
                                          W_mix0, b_mix0, xi, nullptr);

    // ---- layer 1 ----
    k_s1<<<N_ATOMS, 128, 0, stream>>>(xi, W_si1, sbuf);
    k_da<<<(NEA + 255) / 256, 256, 0, stream>>>(dist_a, sw_a, W_da1, da);
    k_mi<<<N_ATOMS, 256, 0, stream>>>(eoff, eidx, edge_dst, distances, sw, sbuf, mi);
    k_ami<<<N_ATOMS, 64, 0, stream>>>(toff, tidx, angle_src, angle_dst, angles, da, ami);
    k_mix<1><<<N_ATOMS, 256, 0, stream>>>(nullptr, nullptr, xi, sbuf, mi, ami,
                                          W_mix1, b_mix1, nullptr, out);
}

// Round 4
// 1292.250 us; speedup vs baseline: 1.4028x; 1.4028x over previous
//
#include <hip/hip_runtime.h>
#include <hip/hip_bf16.h>

typedef __hip_bfloat16 bf16;

#define N_ATOMS 25000
#define NE      800000
#define NEA     300000
#define NT      1600000

#define DIN0 376   // 16 xi + 64 si + 256 mi + 40 ami
#define DIN1 616   // 256 xi + 64 si + 256 mi + 40 ami

__device__ __forceinline__ float tssr2f(float x) {
    float ax = fabsf(x);
    return (ax <= 1.f) ? x : copysignf(2.f * __builtin_sqrtf(ax) - 1.f, x);
}

// ------------------------------------------------------------------
// CSR build
// ------------------------------------------------------------------
__global__ void k_count(const int* __restrict__ esrc, const int* __restrict__ cat,
                        int* __restrict__ ecnt, int* __restrict__ tcnt) {
    int i = blockIdx.x * blockDim.x + threadIdx.x;
    if (i < NE) {
        atomicAdd(&ecnt[esrc[i]], 1);
    } else {
        int j = i - NE;
        if (j < NT) atomicAdd(&tcnt[cat[j]], 1);
    }
}

__global__ __launch_bounds__(1024) void k_scan(const int* cnt0, int* off0, int* cur0,
                                               const int* cnt1, int* off1, int* cur1,
                                               int n) {
    const int* cnt = blockIdx.x ? cnt1 : cnt0;
    int* off = blockIdx.x ? off1 : off0;
    int* cur = blockIdx.x ? cur1 : cur0;
    __shared__ int sh[1024];
    int carry = 0;
    for (int base = 0; base < n; base += 1024) {
        int i = base + (int)threadIdx.x;
        int v = (i < n) ? cnt[i] : 0;
        sh[threadIdx.x] = v;
        __syncthreads();
        for (int d = 1; d < 1024; d <<= 1) {
            int add = (threadIdx.x >= (unsigned)d) ? sh[threadIdx.x - d] : 0;
            __syncthreads();
            sh[threadIdx.x] += add;
            __syncthreads();
        }
        int incl = sh[threadIdx.x];
        int excl = incl - v + carry;
        if (i < n) { off[i] = excl; cur[i] = excl; }
        carry += sh[1023];
        __syncthreads();
    }
    if (threadIdx.x == 0) off[n] = carry;
}

__global__ void k_fill(const int* __restrict__ esrc, const int* __restrict__ cat,
                       int* __restrict__ ecur, int* __restrict__ eidx,
                       int* __restrict__ tcur, int* __restrict__ tidx) {
    int i = blockIdx.x * blockDim.x + threadIdx.x;
    if (i < NE) {
        int p = atomicAdd(&ecur[esrc[i]], 1);
        eidx[p] = i;
    } else {
        int j = i - NE;
        if (j < NT) {
            int p = atomicAdd(&tcur[cat[j]], 1);
            tidx[p] = j;
        }
    }
}

// ------------------------------------------------------------------
// layer 0: ei0[:,0:16) = table[sp]; s = table[sp] @ W_si0 (16x96):
//   cols 0..64 -> ei0[:,16..80), cols 64..96 -> sd
// ------------------------------------------------------------------
__global__ void k_s0(const int* __restrict__ sp, const float* __restrict__ table,
                     const float* __restrict__ W, float* __restrict__ ei0,
                     float* __restrict__ sd) {
    int idx = blockIdx.x * blockDim.x + threadIdx.x;
    if (idx >= N_ATOMS * 112) return;
    int i = idx / 112;
    int c = idx - i * 112;
    int s = sp[i];
    if (c < 16) {
        ei0[i * DIN0 + c] = table[s * 16 + c];
    } else {
        int cc = c - 16;
        float acc = 0.f;
#pragma unroll
        for (int k = 0; k < 16; k++)
            acc += table[s * 16 + k] * W[k * 96 + cc];
        if (cc < 64) ei0[i * DIN0 + 16 + cc] = acc;
        else         sd[i * 32 + cc - 64]    = acc;
    }
}

// layer 1: xi = ei1[:,0:256); s = xi @ W_si1 (256x96)
__global__ __launch_bounds__(128) void k_s1(float* __restrict__ ei1,
                                            const float* __restrict__ W,
                                            float* __restrict__ sd) {
    int i = blockIdx.x;
    __shared__ float x[256];
    for (int k = threadIdx.x; k < 256; k += 128) x[k] = ei1[i * DIN1 + k];
    __syncthreads();
    int c = threadIdx.x;
    if (c < 96) {
        float acc = 0.f;
#pragma unroll 8
        for (int k = 0; k < 256; k++)
            acc += x[k] * W[k * 96 + c];
        if (c < 64) ei1[i * DIN1 + 256 + c] = acc;
        else        sd[i * 32 + c - 64]     = acc;
    }
}

// ------------------------------------------------------------------
// da = (bessel(dist_angle)*switch_angle) @ W_da   -> EA x 8 fp32
// ------------------------------------------------------------------
__global__ void k_da(const float* __restrict__ dist, const float* __restrict__ sw,
                     const float* __restrict__ W, float* __restrict__ da) {
    int e = blockIdx.x * blockDim.x + threadIdx.x;
    if (e >= NEA) return;
    float d = dist[e];
    float s = sw[e];
    float rb[8];
#pragma unroll
    for (int n = 0; n < 8; n++)
        rb[n] = 0.7559289460f * __sinf((n + 1) * 0.8975979010f * d) / d * s;
    float w[8];
#pragma unroll
    for (int c = 0; c < 8; c++) {
        float acc = 0.f;
#pragma unroll
        for (int n = 0; n < 8; n++) acc += rb[n] * W[n * 8 + c];
        w[c] = acc;
    }
#pragma unroll
    for (int c = 0; c < 8; c++) da[e * 8 + c] = w[c];
}

// ------------------------------------------------------------------
// mi[i, n*32+c] = sum_{e in edges(i)} rb[e][n] * sd[edge_dst[e]][c]
// writes to ei[i*stride + t] via mo = ei + (X+64)
// ------------------------------------------------------------------
__global__ __launch_bounds__(256) void k_mi(const int* __restrict__ eoff,
                                            const int* __restrict__ eidx,
                                            const int* __restrict__ edst,
                                            const float* __restrict__ dist,
                                            const float* __restrict__ sw,
                                            const float* __restrict__ sd,
                                            float* __restrict__ mo, int stride) {
    int i = blockIdx.x;
    int beg = eoff[i], end = eoff[i + 1];
    __shared__ float rb_l[4][8];
    __shared__ float sd_l[4][33];
    int t = threadIdx.x;
    int n = t >> 5, c = t & 31;
    float acc = 0.f;
    for (int base = beg; base < end; base += 4) {
        if (t < 32) {
            int j = t >> 3, nn = t & 7;
            float v = 0.f;
            int p = base + j;
            if (p < end) {
                int e = eidx[p];
                float d = dist[e];
                float s = sw[e];
                v = 0.6324555320f * __sinf((nn + 1) * 0.6283185307f * d) / d * s;
            }
            rb_l[j][nn] = v;
        } else if (t >= 64 && t < 192) {
            int j = (t - 64) >> 5, cc = (t - 64) & 31;
            int p = base + j;
            float v = 0.f;
            if (p < end) {
                int e = eidx[p];
                int di = edst[e];
                v = sd[di * 32 + cc];
            }
            sd_l[j][cc] = v;
        }
        __syncthreads();
#pragma unroll
        for (int j = 0; j < 4; j++) acc += rb_l[j][n] * sd_l[j][c];
        __syncthreads();
    }
    mo[i * stride + t] = acc;
}

// ------------------------------------------------------------------
// ami[i, n*8+c] = sum_{tr in trip(i)} cos(n*theta[tr]) * da[asrc][c]*da[adst][c]
// writes to ei[i*stride + t] (t < 40) via ao = ei + (X+320)
// ------------------------------------------------------------------
__global__ __launch_bounds__(64) void k_ami(const int* __restrict__ toff,
                                            const int* __restrict__ tidx,
                                            const int* __restrict__ asrc,
                                            const int* __restrict__ adst,
                                            const float* __restrict__ ang,
                                            const float* __restrict__ da,
                                            float* __restrict__ ao, int stride) {
    int i = blockIdx.x;
    int beg = toff[i], end = toff[i + 1];
    __shared__ float dij_l[8][9];
    __shared__ float xa_l[8][6];
    int t = threadIdx.x;
    int n = t >> 3, c = t & 7;
    float acc = 0.f;
    for (int base = beg; base < end; base += 8) {
        int j = t >> 3, k = t & 7;
        int p = base + j;
        float v = 0.f;
        float th = 0.f;
        if (p < end) {
            int tr = tidx[p];
            int ea = asrc[tr], eb = adst[tr];
            v = da[ea * 8 + k] * da[eb * 8 + k];
            th = ang[tr];
        }
        dij_l[j][k] = v;
        if (k < 5) xa_l[j][k] = __cosf((float)k * th);
        __syncthreads();
        if (t < 40) {
#pragma unroll
            for (int j2 = 0; j2 < 8; j2++) acc += xa_l[j2][n] * dij_l[j2][c];
        }
        __syncthreads();
    }
    if (t < 40) ao[i * stride + t] = acc;
}

// ------------------------------------------------------------------
// Tiled GEMM: dxi = tssr2(ei @ W + b)
// MT=32 atoms x 256 cols per block; KT=16; thread tile 8 atoms x 4 cols.
// LAYER 0: out = ei1 (stride DIN1), writes xi part.
// LAYER 1: out[atom*256+col] = ei1_xi + v.
// ------------------------------------------------------------------
template <int LAYER>
__global__ __launch_bounds__(256) void k_gemm(const float* __restrict__ ei,
                                              const float* __restrict__ W,
                                              const float* __restrict__ bias,
                                              const float* __restrict__ skip,
                                              float* __restrict__ out) {
    constexpr int DIN = (LAYER == 0) ? DIN0 : DIN1;
    constexpr int KT = 16, MT = 32;
    constexpr int ESTR = 36;  // Et row stride (16B-aligned float4 reads, 2-way banks)
    __shared__ float Wt[KT][256];
    __shared__ float Et[KT][ESTR];
    int t = threadIdx.x;
    int a0 = blockIdx.x * MT;
    int cg = t & 63, ag = t >> 6;
    int col = cg * 4;
    float acc[8][4];
#pragma unroll
    for (int r = 0; r < 8; r++)
#pragma unroll
        for (int j = 0; j < 4; j++) acc[r][j] = 0.f;

    constexpr int NTILE = (DIN + KT - 1) / KT;
    for (int kt = 0; kt < NTILE; kt++) {
        int k0 = kt * KT;
        __syncthreads();
        // stage W tile: 16 rows x 256 cols, 4x float4 per thread
#pragma unroll
        for (int q = 0; q < 4; q++) {
            int kk = 4 * q + ag;
            float4 v = make_float4(0.f, 0.f, 0.f, 0.f);
            if (k0 + kk < DIN) v = *(const float4*)&W[(k0 + kk) * 256 + col];
            *(float4*)&Wt[kk][col] = v;
        }
        // stage ei tile: 16 k x 32 atoms (transposed), float2 per thread
        {
            int atom = t >> 3;
            int kk = (t & 7) * 2;
            float2 v = make_float2(0.f, 0.f);
            int ga = a0 + atom;
            if (ga < N_ATOMS && k0 + kk < DIN)
                v = *(const float2*)&ei[(size_t)ga * DIN + k0 + kk];
            Et[kk][atom] = v.x;
            Et[kk + 1][atom] = v.y;
        }
        __syncthreads();
#pragma unroll 4
        for (int kk = 0; kk < KT; kk++) {
            float4 w = *(const float4*)&Wt[kk][col];
            float4 e0 = *(const float4*)&Et[kk][ag * 8];
            float4 e1 = *(const float4*)&Et[kk][ag * 8 + 4];
            float ev[8] = {e0.x, e0.y, e0.z, e0.w, e1.x, e1.y, e1.z, e1.w};
#pragma unroll
            for (int r = 0; r < 8; r++) {
                acc[r][0] += ev[r] * w.x;
                acc[r][1] += ev[r] * w.y;
                acc[r][2] += ev[r] * w.z;
                acc[r][3] += ev[r] * w.w;
            }
        }
    }
    float4 bb = *(const float4*)&bias[col];
#pragma unroll
    for (int r = 0; r < 8; r++) {
        int atom = a0 + ag * 8 + r;
        if (atom >= N_ATOMS) break;
        float4 v;
        v.x = tssr2f(acc[r][0] + bb.x);
        v.y = tssr2f(acc[r][1] + bb.y);
        v.z = tssr2f(acc[r][2] + bb.z);
        v.w = tssr2f(acc[r][3] + bb.w);
        if (LAYER == 0) {
            *(float4*)&out[(size_t)atom * DIN1 + col] = v;
        } else {
            float4 x = *(const float4*)&skip[(size_t)atom * DIN1 + col];
            v.x += x.x; v.y += x.y; v.z += x.z; v.w += x.w;
            *(float4*)&out[(size_t)atom * 256 + col] = v;
        }
    }
}

// ------------------------------------------------------------------
extern "C" void kernel_launch(void* const* d_in, const int* in_sizes, int n_in,
                              void* d_out, int out_size, void* d_ws, size_t ws_size,
                              hipStream_t stream) {
    const int*   species     = (const int*)d_in[0];
    const int*   edge_src    = (const int*)d_in[1];
    const int*   edge_dst    = (const int*)d_in[2];
    const float* distances   = (const float*)d_in[3];
    const float* sw          = (const float*)d_in[4];
    const float* angles      = (const float*)d_in[5];
    const int*   angle_src   = (const int*)d_in[6];
    const int*   angle_dst   = (const int*)d_in[7];
    const int*   central     = (const int*)d_in[8];
    const float* dist_a      = (const float*)d_in[9];
    const float* sw_a        = (const float*)d_in[10];
    const float* table       = (const float*)d_in[11];
    const float* W_si0       = (const float*)d_in[12];
    const float* W_si1       = (const float*)d_in[13];
    const float* W_da0       = (const float*)d_in[14];
    const float* W_da1       = (const float*)d_in[15];
    const float* W_mix0      = (const float*)d_in[16];
    const float* b_mix0      = (const float*)d_in[17];
    const float* W_mix1      = (const float*)d_in[18];
    const float* b_mix1      = (const float*)d_in[19];
    float* out = (float*)d_out;

    char* p = (char*)d_ws;
    auto alloc = [&](size_t bytes) {
        char* r = p;
        p += (bytes + 255) & ~(size_t)255;
        return (void*)r;
    };
    float* ei0 = (float*)alloc((size_t)N_ATOMS * DIN0 * 4);
    float* ei1 = (float*)alloc((size_t)N_ATOMS * DIN1 * 4);
    float* sd  = (float*)alloc((size_t)N_ATOMS * 32 * 4);
    float* da  = (float*)alloc((size_t)NEA * 8 * 4);
    int* ecnt = (int*)alloc((size_t)N_ATOMS * 4);
    int* eoff = (int*)alloc((size_t)(N_ATOMS + 1) * 4);
    int* ecur = (int*)alloc((size_t)N_ATOMS * 4);
    int* eidx = (int*)alloc((size_t)NE * 4);
    int* tcnt = (int*)alloc((size_t)N_ATOMS * 4);
    int* toff = (int*)alloc((size_t)(N_ATOMS + 1) * 4);
    int* tcur = (int*)alloc((size_t)N_ATOMS * 4);
    int* tidx = (int*)alloc((size_t)NT * 4);
    (void)ws_size;

    hipMemsetAsync(ecnt, 0, (size_t)N_ATOMS * 4, stream);
    hipMemsetAsync(tcnt, 0, (size_t)N_ATOMS * 4, stream);

    int nct = NE + NT;
    k_count<<<(nct + 255) / 256, 256, 0, stream>>>(edge_src, central, ecnt, tcnt);
    k_scan<<<2, 1024, 0, stream>>>(ecnt, eoff, ecur, tcnt, toff, tcur, N_ATOMS);
    k_fill<<<(nct + 255) / 256, 256, 0, stream>>>(edge_src, central, ecur, eidx, tcur, tidx);

    int gemm_grid = (N_ATOMS + 31) / 32;

    // ---- layer 0 ----
    k_s0<<<(N_ATOMS * 112 + 255) / 256, 256, 0, stream>>>(species, table, W_si0, ei0, sd);
    k_da<<<(NEA + 255) / 256, 256, 0, stream>>>(dist_a, sw_a, W_da0, da);
    k_mi<<<N_ATOMS, 256, 0, stream>>>(eoff, eidx, edge_dst, distances, sw, sd,
                                      ei0 + 80, DIN0);
    k_ami<<<N_ATOMS, 64, 0, stream>>>(toff, tidx, angle_src, angle_dst, angles, da,
                                      ei0 + 336, DIN0);
    k_gemm<0><<<gemm_grid, 256, 0, stream>>>(ei0, W_mix0, b_mix0, nullptr, ei1);

    // ---- layer 1 ----
    k_s1<<<N_ATOMS, 128, 0, stream>>>(ei1, W_si1, sd);
    k_da<<<(NEA + 255) / 256, 256, 0, stream>>>(dist_a, sw_a, W_da1, da);
    k_mi<<<N_ATOMS, 256, 0, stream>>>(eoff, eidx, edge_dst, distances, sw, sd,
                                      ei1 + 320, DIN1);
    k_ami<<<N_ATOMS, 64, 0, stream>>>(toff, tidx, angle_src, angle_dst, angles, da,
                                      ei1 + 576, DIN1);
    k_gemm<1><<<gemm_grid, 256, 0, stream>>>(ei1, W_mix1, b_mix1, ei1, out);
}

// Round 5
// 914.347 us; speedup vs baseline: 1.9826x; 1.4133x over previous
//
#include <hip/hip_runtime.h>
#include <hip/hip_bf16.h>

typedef __hip_bfloat16 bf16;

#define N_ATOMS 25000
#define NE      800000
#define NEA     300000
#define NT      1600000
#define APB     64                    // atoms per bucket
#define NBUK    ((N_ATOMS + APB - 1) / APB)   // 391

#define DIN0 376   // 16 xi + 64 si + 256 mi + 40 ami
#define DIN1 616   // 256 xi + 64 si + 256 mi + 40 ami

__device__ __forceinline__ float tssr2f(float x) {
    float ax = fabsf(x);
    return (ax <= 1.f) ? x : copysignf(2.f * __builtin_sqrtf(ax) - 1.f, x);
}

// ------------------------------------------------------------------
// CSR build: histogram + scan
// ------------------------------------------------------------------
__global__ void k_count(const int* __restrict__ esrc, const int* __restrict__ cat,
                        int* __restrict__ ecnt, int* __restrict__ tcnt) {
    int i = blockIdx.x * blockDim.x + threadIdx.x;
    if (i < NE) {
        atomicAdd(&ecnt[esrc[i]], 1);
    } else {
        int j = i - NE;
        if (j < NT) atomicAdd(&tcnt[cat[j]], 1);
    }
}

__global__ __launch_bounds__(1024) void k_scan(const int* cnt0, int* off0,
                                               const int* cnt1, int* off1,
                                               int n) {
    const int* cnt = blockIdx.x ? cnt1 : cnt0;
    int* off = blockIdx.x ? off1 : off0;
    __shared__ int sh[1024];
    int carry = 0;
    for (int base = 0; base < n; base += 1024) {
        int i = base + (int)threadIdx.x;
        int v = (i < n) ? cnt[i] : 0;
        sh[threadIdx.x] = v;
        __syncthreads();
        for (int d = 1; d < 1024; d <<= 1) {
            int add = (threadIdx.x >= (unsigned)d) ? sh[threadIdx.x - d] : 0;
            __syncthreads();
            sh[threadIdx.x] += add;
            __syncthreads();
        }
        int incl = sh[threadIdx.x];
        int excl = incl - v + carry;
        if (i < n) off[i] = excl;
        carry += sh[1023];
        __syncthreads();
    }
    if (threadIdx.x == 0) off[n] = carry;
}

__global__ void k_initcur(const int* __restrict__ eoff, const int* __restrict__ toff,
                          int* __restrict__ gce, int* __restrict__ gct) {
    int b = blockIdx.x * blockDim.x + threadIdx.x;
    if (b < NBUK) {
        gce[b] = eoff[b * APB];
        gct[b] = toff[b * APB];
    }
}

// ------------------------------------------------------------------
// Phase A: bin payloads into coarse buckets (bucket = key >> 6).
// Payload: EDGE ? (dist, sw, dst, src) : (ang, asrc, adst, cat); key in .w
// ------------------------------------------------------------------
template <bool EDGE>
__global__ __launch_bounds__(512) void k_binA(const float* __restrict__ fA,
                                              const float* __restrict__ fB,
                                              const int* __restrict__ iB,
                                              const int* __restrict__ iC,
                                              const int* __restrict__ key,
                                              int* __restrict__ gcur,
                                              float4* __restrict__ buk, int n) {
    __shared__ int cnt[NBUK];
    __shared__ int rbase[NBUK];
    int t = threadIdx.x;
    for (int b = t; b < NBUK; b += 512) cnt[b] = 0;
    __syncthreads();
    int base = blockIdx.x * 4096;
    float4 pay[8];
    int bk[8], off[8];
#pragma unroll
    for (int k = 0; k < 8; k++) {
        int idx = base + k * 512 + t;
        bk[k] = -1;
        if (idx < n) {
            float4 p;
            p.x = fA[idx];
            p.y = EDGE ? fB[idx] : __int_as_float(iB[idx]);
            p.z = __int_as_float(iC[idx]);
            int ky = key[idx];
            p.w = __int_as_float(ky);
            pay[k] = p;
            bk[k] = ky >> 6;
            off[k] = atomicAdd(&cnt[bk[k]], 1);
        }
    }
    __syncthreads();
    for (int b = t; b < NBUK; b += 512)
        if (cnt[b]) rbase[b] = atomicAdd(&gcur[b], cnt[b]);
    __syncthreads();
#pragma unroll
    for (int k = 0; k < 8; k++)
        if (bk[k] >= 0) buk[rbase[bk[k]] + off[k]] = pay[k];
}

// ------------------------------------------------------------------
// Phase B: one workgroup per bucket; place payloads at exact CSR slots.
// Single workgroup owns the destination window -> L2 write-combining.
// ------------------------------------------------------------------
__global__ __launch_bounds__(256) void k_binB(const int* __restrict__ off,
                                              const float4* __restrict__ buk,
                                              float4* __restrict__ fin) {
    int b = blockIdx.x;
    int lo = b * APB;
    int hi = min(lo + APB, N_ATOMS);
    __shared__ int cur[APB];
    int t = threadIdx.x;
    if (t < hi - lo) cur[t] = off[lo + t];
    __syncthreads();
    int pbeg = off[lo], pend = off[hi];
    for (int p = pbeg + t; p < pend; p += 256) {
        float4 pay = buk[p];
        int atom = __float_as_int(pay.w);
        int slot = atomicAdd(&cur[atom - lo], 1);
        fin[slot] = pay;
    }
}

// ------------------------------------------------------------------
// layer 0: ei0[:,0:16) = table[sp]; s = table[sp] @ W_si0 (16x96)
// ------------------------------------------------------------------
__global__ void k_s0(const int* __restrict__ sp, const float* __restrict__ table,
                     const float* __restrict__ W, float* __restrict__ ei0,
                     float* __restrict__ sd) {
    int idx = blockIdx.x * blockDim.x + threadIdx.x;
    if (idx >= N_ATOMS * 112) return;
    int i = idx / 112;
    int c = idx - i * 112;
    int s = sp[i];
    if (c < 16) {
        ei0[i * DIN0 + c] = table[s * 16 + c];
    } else {
        int cc = c - 16;
        float acc = 0.f;
#pragma unroll
        for (int k = 0; k < 16; k++)
            acc += table[s * 16 + k] * W[k * 96 + cc];
        if (cc < 64) ei0[i * DIN0 + 16 + cc] = acc;
        else         sd[i * 32 + cc - 64]    = acc;
    }
}

// layer 1: xi = ei1[:,0:256); s = xi @ W_si1 (256x96)
__global__ __launch_bounds__(128) void k_s1(float* __restrict__ ei1,
                                            const float* __restrict__ W,
                                            float* __restrict__ sd) {
    int i = blockIdx.x;
    __shared__ float x[256];
    for (int k = threadIdx.x; k < 256; k += 128) x[k] = ei1[i * DIN1 + k];
    __syncthreads();
    int c = threadIdx.x;
    if (c < 96) {
        float acc = 0.f;
#pragma unroll 8
        for (int k = 0; k < 256; k++)
            acc += x[k] * W[k * 96 + c];
        if (c < 64) ei1[i * DIN1 + 256 + c] = acc;
        else        sd[i * 32 + c - 64]     = acc;
    }
}

// ------------------------------------------------------------------
// da = (bessel(dist_angle)*switch_angle) @ W_da   -> EA x 8 fp32
// ------------------------------------------------------------------
__global__ void k_da(const float* __restrict__ dist, const float* __restrict__ sw,
                     const float* __restrict__ W, float* __restrict__ da) {
    int e = blockIdx.x * blockDim.x + threadIdx.x;
    if (e >= NEA) return;
    float d = dist[e];
    float s = sw[e];
    float rb[8];
#pragma unroll
    for (int n = 0; n < 8; n++)
        rb[n] = 0.7559289460f * __sinf((n + 1) * 0.8975979010f * d) / d * s;
    float w[8];
#pragma unroll
    for (int c = 0; c < 8; c++) {
        float acc = 0.f;
#pragma unroll
        for (int n = 0; n < 8; n++) acc += rb[n] * W[n * 8 + c];
        w[c] = acc;
    }
#pragma unroll
    for (int c = 0; c < 8; c++) da[e * 8 + c] = w[c];
}

// ------------------------------------------------------------------
// mi: per-atom segment of epay (sequential), 8 edges/iter
// ------------------------------------------------------------------
__global__ __launch_bounds__(256) void k_mi(const int* __restrict__ eoff,
                                            const float4* __restrict__ epay,
                                            const float* __restrict__ sd,
                                            float* __restrict__ mo, int stride) {
    int i = blockIdx.x;
    int beg = eoff[i], end = eoff[i + 1];
    __shared__ float rb_l[8][9];
    __shared__ float sd_l[8][33];
    int t = threadIdx.x;
    int n = t >> 5, c = t & 31;
    float acc = 0.f;
    for (int base = beg; base < end; base += 8) {
        int j = t >> 5, cc = t & 31;
        int p = base + j;
        float v = 0.f;
        if (p < end) {
            float4 ep = epay[p];
            int di = __float_as_int(ep.z);
            v = sd[di * 32 + cc];
        }
        sd_l[j][cc] = v;
        if (t < 64) {
            int jj = t >> 3, nn = t & 7;
            int pp = base + jj;
            float r = 0.f;
            if (pp < end) {
                float4 ep = epay[pp];
                float d = ep.x, s = ep.y;
                r = 0.6324555320f * __sinf((nn + 1) * 0.6283185307f * d) / d * s;
            }
            rb_l[jj][nn] = r;
        }
        __syncthreads();
#pragma unroll
        for (int j2 = 0; j2 < 8; j2++) acc += rb_l[j2][n] * sd_l[j2][c];
        __syncthreads();
    }
    mo[i * stride + t] = acc;
}

// ------------------------------------------------------------------
// ami: per-atom segment of tpay (sequential), 8 triplets/iter
// ------------------------------------------------------------------
__global__ __launch_bounds__(64) void k_ami(const int* __restrict__ toff,
                                            const float4* __restrict__ tpay,
                                            const float* __restrict__ da,
                                            float* __restrict__ ao, int stride) {
    int i = blockIdx.x;
    int beg = toff[i], end = toff[i + 1];
    __shared__ float dij_l[8][9];
    __shared__ float xa_l[8][6];
    int t = threadIdx.x;
    int n = t >> 3, c = t & 7;
    float acc = 0.f;
    for (int base = beg; base < end; base += 8) {
        int j = t >> 3, k = t & 7;
        int p = base + j;
        float v = 0.f, th = 0.f;
        if (p < end) {
            float4 tp = tpay[p];
            int ea = __float_as_int(tp.y), eb = __float_as_int(tp.z);
            v = da[ea * 8 + k] * da[eb * 8 + k];
            th = tp.x;
        }
        dij_l[j][k] = v;
        if (k < 5) xa_l[j][k] = __cosf((float)k * th);
        __syncthreads();
        if (t < 40) {
#pragma unroll
            for (int j2 = 0; j2 < 8; j2++) acc += xa_l[j2][n] * dij_l[j2][c];
        }
        __syncthreads();
    }
    if (t < 40) ao[i * stride + t] = acc;
}

// ------------------------------------------------------------------
// Tiled GEMM: dxi = tssr2(ei @ W + b)
// ------------------------------------------------------------------
template <int LAYER>
__global__ __launch_bounds__(256) void k_gemm(const float* __restrict__ ei,
                                              const float* __restrict__ W,
                                              const float* __restrict__ bias,
                                              const float* __restrict__ skip,
                                              float* __restrict__ out) {
    constexpr int DIN = (LAYER == 0) ? DIN0 : DIN1;
    constexpr int KT = 16, MT = 32;
    constexpr int ESTR = 36;
    __shared__ float Wt[KT][256];
    __shared__ float Et[KT][ESTR];
    int t = threadIdx.x;
    int a0 = blockIdx.x * MT;
    int cg = t & 63, ag = t >> 6;
    int col = cg * 4;
    float acc[8][4];
#pragma unroll
    for (int r = 0; r < 8; r++)
#pragma unroll
        for (int j = 0; j < 4; j++) acc[r][j] = 0.f;

    constexpr int NTILE = (DIN + KT - 1) / KT;
    for (int kt = 0; kt < NTILE; kt++) {
        int k0 = kt * KT;
        __syncthreads();
#pragma unroll
        for (int q = 0; q < 4; q++) {
            int kk = 4 * q + ag;
            float4 v = make_float4(0.f, 0.f, 0.f, 0.f);
            if (k0 + kk < DIN) v = *(const float4*)&W[(k0 + kk) * 256 + col];
            *(float4*)&Wt[kk][col] = v;
        }
        {
            int atom = t >> 3;
            int kk = (t & 7) * 2;
            float2 v = make_float2(0.f, 0.f);
            int ga = a0 + atom;
            if (ga < N_ATOMS && k0 + kk < DIN)
                v = *(const float2*)&ei[(size_t)ga * DIN + k0 + kk];
            Et[kk][atom] = v.x;
            Et[kk + 1][atom] = v.y;
        }
        __syncthreads();
#pragma unroll 4
        for (int kk = 0; kk < KT; kk++) {
            float4 w = *(const float4*)&Wt[kk][col];
            float4 e0 = *(const float4*)&Et[kk][ag * 8];
            float4 e1 = *(const float4*)&Et[kk][ag * 8 + 4];
            float ev[8] = {e0.x, e0.y, e0.z, e0.w, e1.x, e1.y, e1.z, e1.w};
#pragma unroll
            for (int r = 0; r < 8; r++) {
                acc[r][0] += ev[r] * w.x;
                acc[r][1] += ev[r] * w.y;
                acc[r][2] += ev[r] * w.z;
                acc[r][3] += ev[r] * w.w;
            }
        }
    }
    float4 bb = *(const float4*)&bias[col];
#pragma unroll
    for (int r = 0; r < 8; r++) {
        int atom = a0 + ag * 8 + r;
        if (atom >= N_ATOMS) break;
        float4 v;
        v.x = tssr2f(acc[r][0] + bb.x);
        v.y = tssr2f(acc[r][1] + bb.y);
        v.z = tssr2f(acc[r][2] + bb.z);
        v.w = tssr2f(acc[r][3] + bb.w);
        if (LAYER == 0) {
            *(float4*)&out[(size_t)atom * DIN1 + col] = v;
        } else {
            float4 x = *(const float4*)&skip[(size_t)atom * DIN1 + col];
            v.x += x.x; v.y += x.y; v.z += x.z; v.w += x.w;
            *(float4*)&out[(size_t)atom * 256 + col] = v;
        }
    }
}

// ------------------------------------------------------------------
extern "C" void kernel_launch(void* const* d_in, const int* in_sizes, int n_in,
                              void* d_out, int out_size, void* d_ws, size_t ws_size,
                              hipStream_t stream) {
    const int*   species     = (const int*)d_in[0];
    const int*   edge_src    = (const int*)d_in[1];
    const int*   edge_dst    = (const int*)d_in[2];
    const float* distances   = (const float*)d_in[3];
    const float* sw          = (const float*)d_in[4];
    const float* angles      = (const float*)d_in[5];
    const int*   angle_src   = (const int*)d_in[6];
    const int*   angle_dst   = (const int*)d_in[7];
    const int*   central     = (const int*)d_in[8];
    const float* dist_a      = (const float*)d_in[9];
    const float* sw_a        = (const float*)d_in[10];
    const float* table       = (const float*)d_in[11];
    const float* W_si0       = (const float*)d_in[12];
    const float* W_si1       = (const float*)d_in[13];
    const float* W_da0       = (const float*)d_in[14];
    const float* W_da1       = (const float*)d_in[15];
    const float* W_mix0      = (const float*)d_in[16];
    const float* b_mix0      = (const float*)d_in[17];
    const float* W_mix1      = (const float*)d_in[18];
    const float* b_mix1      = (const float*)d_in[19];
    float* out = (float*)d_out;

    char* p = (char*)d_ws;
    auto alloc = [&](size_t bytes) {
        char* r = p;
        p += (bytes + 255) & ~(size_t)255;
        return (void*)r;
    };
    float*  ei0  = (float*)alloc((size_t)N_ATOMS * DIN0 * 4);
    float*  ei1  = (float*)alloc((size_t)N_ATOMS * DIN1 * 4);
    float*  sd   = (float*)alloc((size_t)N_ATOMS * 32 * 4);
    float*  da   = (float*)alloc((size_t)NEA * 8 * 4);
    float4* epay = (float4*)alloc((size_t)NE * 16);
    float4* tpay = (float4*)alloc((size_t)NT * 16);
    int* ecnt = (int*)alloc((size_t)N_ATOMS * 4);
    int* eoff = (int*)alloc((size_t)(N_ATOMS + 1) * 4);
    int* tcnt = (int*)alloc((size_t)N_ATOMS * 4);
    int* toff = (int*)alloc((size_t)(N_ATOMS + 1) * 4);
    int* gce  = (int*)alloc((size_t)NBUK * 4);
    int* gct  = (int*)alloc((size_t)NBUK * 4);
    (void)ws_size;

    // bucket staging arrays alias ei1 (which is only written after binning)
    float4* tbuk = (float4*)ei1;
    float4* ebuk = (float4*)((char*)ei1 + (size_t)NT * 16);

    hipMemsetAsync(ecnt, 0, (size_t)N_ATOMS * 4, stream);
    hipMemsetAsync(tcnt, 0, (size_t)N_ATOMS * 4, stream);

    int nct = NE + NT;
    k_count<<<(nct + 255) / 256, 256, 0, stream>>>(edge_src, central, ecnt, tcnt);
    k_scan<<<2, 1024, 0, stream>>>(ecnt, eoff, tcnt, toff, N_ATOMS);
    k_initcur<<<(NBUK + 255) / 256, 256, 0, stream>>>(eoff, toff, gce, gct);

    k_binA<true><<<(NE + 4095) / 4096, 512, 0, stream>>>(
        distances, sw, nullptr, edge_dst, edge_src, gce, ebuk, NE);
    k_binA<false><<<(NT + 4095) / 4096, 512, 0, stream>>>(
        angles, nullptr, angle_src, angle_dst, central, gct, tbuk, NT);
    k_binB<<<NBUK, 256, 0, stream>>>(eoff, ebuk, epay);
    k_binB<<<NBUK, 256, 0, stream>>>(toff, tbuk, tpay);

    int gemm_grid = (N_ATOMS + 31) / 32;

    // ---- layer 0 ----
    k_s0<<<(N_ATOMS * 112 + 255) / 256, 256, 0, stream>>>(species, table, W_si0, ei0, sd);
    k_da<<<(NEA + 255) / 256, 256, 0, stream>>>(dist_a, sw_a, W_da0, da);
    k_mi<<<N_ATOMS, 256, 0, stream>>>(eoff, epay, sd, ei0 + 80, DIN0);
    k_ami<<<N_ATOMS, 64, 0, stream>>>(toff, tpay, da, ei0 + 336, DIN0);
    k_gemm<0><<<gemm_grid, 256, 0, stream>>>(ei0, W_mix0, b_mix0, nullptr, ei1);

    // ---- layer 1 ----
    k_s1<<<N_ATOMS, 128, 0, stream>>>(ei1, W_si1, sd);
    k_da<<<(NEA + 255) / 256, 256, 0, stream>>>(dist_a, sw_a, W_da1, da);
    k_mi<<<N_ATOMS, 256, 0, stream>>>(eoff, epay, sd, ei1 + 320, DIN1);
    k_ami<<<N_ATOMS, 64, 0, stream>>>(toff, tpay, da, ei1 + 576, DIN1);
    k_gemm<1><<<gemm_grid, 256, 0, stream>>>(ei1, W_mix1, b_mix1, ei1, out);
}

// Round 6
// 752.281 us; speedup vs baseline: 2.4097x; 1.2154x over previous
//
#include <hip/hip_runtime.h>
#include <hip/hip_bf16.h>

typedef __hip_bfloat16 bf16;
typedef __bf16 bf8 __attribute__((ext_vector_type(8)));
typedef float  f4  __attribute__((ext_vector_type(4)));

#define N_ATOMS 25000
#define NE      800000
#define NEA     300000
#define NT      1600000
#define APB     64
#define NBUK    ((N_ATOMS + APB - 1) / APB)   // 391

#define DIN0  376   // 16 xi + 64 si + 256 mi + 40 ami
#define DIN1  616   // 256 xi + 64 si + 256 mi + 40 ami
#define DINP0 384   // padded (mult of 32)
#define DINP1 640

__device__ __forceinline__ float tssr2f(float x) {
    float ax = fabsf(x);
    return (ax <= 1.f) ? x : copysignf(2.f * __builtin_sqrtf(ax) - 1.f, x);
}

// ------------------------------------------------------------------
// CSR build: histogram + scan
// ------------------------------------------------------------------
__global__ void k_count(const int* __restrict__ esrc, const int* __restrict__ cat,
                        int* __restrict__ ecnt, int* __restrict__ tcnt) {
    int i = blockIdx.x * blockDim.x + threadIdx.x;
    if (i < NE) {
        atomicAdd(&ecnt[esrc[i]], 1);
    } else {
        int j = i - NE;
        if (j < NT) atomicAdd(&tcnt[cat[j]], 1);
    }
}

__global__ __launch_bounds__(1024) void k_scan(const int* cnt0, int* off0,
                                               const int* cnt1, int* off1,
                                               int n) {
    const int* cnt = blockIdx.x ? cnt1 : cnt0;
    int* off = blockIdx.x ? off1 : off0;
    __shared__ int sh[1024];
    int carry = 0;
    for (int base = 0; base < n; base += 1024) {
        int i = base + (int)threadIdx.x;
        int v = (i < n) ? cnt[i] : 0;
        sh[threadIdx.x] = v;
        __syncthreads();
        for (int d = 1; d < 1024; d <<= 1) {
            int add = (threadIdx.x >= (unsigned)d) ? sh[threadIdx.x - d] : 0;
            __syncthreads();
            sh[threadIdx.x] += add;
            __syncthreads();
        }
        int incl = sh[threadIdx.x];
        int excl = incl - v + carry;
        if (i < n) off[i] = excl;
        carry += sh[1023];
        __syncthreads();
    }
    if (threadIdx.x == 0) off[n] = carry;
}

__global__ void k_initcur(const int* __restrict__ eoff, const int* __restrict__ toff,
                          int* __restrict__ gce, int* __restrict__ gct) {
    int b = blockIdx.x * blockDim.x + threadIdx.x;
    if (b < NBUK) {
        gce[b] = eoff[b * APB];
        gct[b] = toff[b * APB];
    }
}

// ------------------------------------------------------------------
// Phase A: bin payloads into coarse buckets (bucket = key >> 6)
// ------------------------------------------------------------------
template <bool EDGE>
__global__ __launch_bounds__(512) void k_binA(const float* __restrict__ fA,
                                              const float* __restrict__ fB,
                                              const int* __restrict__ iB,
                                              const int* __restrict__ iC,
                                              const int* __restrict__ key,
                                              int* __restrict__ gcur,
                                              float4* __restrict__ buk, int n) {
    __shared__ int cnt[NBUK];
    __shared__ int rbase[NBUK];
    int t = threadIdx.x;
    for (int b = t; b < NBUK; b += 512) cnt[b] = 0;
    __syncthreads();
    int base = blockIdx.x * 4096;
    float4 pay[8];
    int bk[8], off[8];
#pragma unroll
    for (int k = 0; k < 8; k++) {
        int idx = base + k * 512 + t;
        bk[k] = -1;
        if (idx < n) {
            float4 p;
            p.x = fA[idx];
            p.y = EDGE ? fB[idx] : __int_as_float(iB[idx]);
            p.z = __int_as_float(iC[idx]);
            int ky = key[idx];
            p.w = __int_as_float(ky);
            pay[k] = p;
            bk[k] = ky >> 6;
            off[k] = atomicAdd(&cnt[bk[k]], 1);
        }
    }
    __syncthreads();
    for (int b = t; b < NBUK; b += 512)
        if (cnt[b]) rbase[b] = atomicAdd(&gcur[b], cnt[b]);
    __syncthreads();
#pragma unroll
    for (int k = 0; k < 8; k++)
        if (bk[k] >= 0) buk[rbase[bk[k]] + off[k]] = pay[k];
}

// ------------------------------------------------------------------
// Phase B: one workgroup per bucket -> exact CSR slots
// ------------------------------------------------------------------
__global__ __launch_bounds__(256) void k_binB(const int* __restrict__ off,
                                              const float4* __restrict__ buk,
                                              float4* __restrict__ fin) {
    int b = blockIdx.x;
    int lo = b * APB;
    int hi = min(lo + APB, N_ATOMS);
    __shared__ int cur[APB];
    int t = threadIdx.x;
    if (t < hi - lo) cur[t] = off[lo + t];
    __syncthreads();
    int pbeg = off[lo], pend = off[hi];
    for (int p = pbeg + t; p < pend; p += 256) {
        float4 pay = buk[p];
        int atom = __float_as_int(pay.w);
        int slot = atomicAdd(&cur[atom - lo], 1);
        fin[slot] = pay;
    }
}

// ------------------------------------------------------------------
// W -> bf16 fragment layout: frag f = (chunk*16 + ctile)*64 + lane
//   holds W[chunk*32 + (lane>>4)*8 + j][ctile*16 + (lane&15)], j=0..7
// ------------------------------------------------------------------
__global__ void k_wprep(const float* __restrict__ W, bf8* __restrict__ Wf,
                        int DIN, int nfrag) {
    int f = blockIdx.x * blockDim.x + threadIdx.x;
    if (f >= nfrag) return;
    int lane = f & 63;
    int tile = (f >> 6) & 15;
    int chunk = f >> 10;
    int n = tile * 16 + (lane & 15);
    int kb = chunk * 32 + (lane >> 4) * 8;
    bf8 v;
#pragma unroll
    for (int j = 0; j < 8; j++) {
        int k = kb + j;
        v[j] = (__bf16)((k < DIN) ? W[k * 256 + n] : 0.f);
    }
    Wf[f] = v;
}

// ------------------------------------------------------------------
// layer 0: ei0[:,0:16) = table[sp]; s = table[sp] @ W_si0 (16x96); pad zeros
// ------------------------------------------------------------------
__global__ void k_s0(const int* __restrict__ sp, const float* __restrict__ table,
                     const float* __restrict__ W, float* __restrict__ ei0,
                     float* __restrict__ sd) {
    int idx = blockIdx.x * blockDim.x + threadIdx.x;
    if (idx >= N_ATOMS * 120) return;
    int i = idx / 120;
    int c = idx - i * 120;
    if (c >= 112) {  // zero pad cols 376..384
        ei0[(size_t)i * DINP0 + 376 + (c - 112)] = 0.f;
        return;
    }
    int s = sp[i];
    if (c < 16) {
        ei0[(size_t)i * DINP0 + c] = table[s * 16 + c];
    } else {
        int cc = c - 16;
        float acc = 0.f;
#pragma unroll
        for (int k = 0; k < 16; k++)
            acc += table[s * 16 + k] * W[k * 96 + cc];
        if (cc < 64) ei0[(size_t)i * DINP0 + 16 + cc] = acc;
        else         sd[i * 32 + cc - 64]             = acc;
    }
}

// layer 1: xi = ei1[:,0:256); s = xi @ W_si1 (256x96); pad zeros
__global__ __launch_bounds__(128) void k_s1(float* __restrict__ ei1,
                                            const float* __restrict__ W,
                                            float* __restrict__ sd) {
    int i = blockIdx.x;
    __shared__ float x[256];
    for (int k = threadIdx.x; k < 256; k += 128) x[k] = ei1[(size_t)i * DINP1 + k];
    __syncthreads();
    int c = threadIdx.x;
    if (c < 96) {
        float acc = 0.f;
#pragma unroll 8
        for (int k = 0; k < 256; k++)
            acc += x[k] * W[k * 96 + c];
        if (c < 64) ei1[(size_t)i * DINP1 + 256 + c] = acc;
        else        sd[i * 32 + c - 64]              = acc;
    } else if (c < 120) {  // zero pad cols 616..640
        ei1[(size_t)i * DINP1 + 616 + (c - 96)] = 0.f;
    }
}

// ------------------------------------------------------------------
// da = (bessel(dist_angle)*switch_angle) @ W_da   -> EA x 8 fp32
// ------------------------------------------------------------------
__global__ void k_da(const float* __restrict__ dist, const float* __restrict__ sw,
                     const float* __restrict__ W, float* __restrict__ da) {
    int e = blockIdx.x * blockDim.x + threadIdx.x;
    if (e >= NEA) return;
    float d = dist[e];
    float s = sw[e];
    float rb[8];
#pragma unroll
    for (int n = 0; n < 8; n++)
        rb[n] = 0.7559289460f * __sinf((n + 1) * 0.8975979010f * d) / d * s;
    float w[8];
#pragma unroll
    for (int c = 0; c < 8; c++) {
        float acc = 0.f;
#pragma unroll
        for (int n = 0; n < 8; n++) acc += rb[n] * W[n * 8 + c];
        w[c] = acc;
    }
#pragma unroll
    for (int c = 0; c < 8; c++) da[e * 8 + c] = w[c];
}

// ------------------------------------------------------------------
// mi: per-atom segment of epay (sequential), 8 edges/iter
// ------------------------------------------------------------------
__global__ __launch_bounds__(256) void k_mi(const int* __restrict__ eoff,
                                            const float4* __restrict__ epay,
                                            const float* __restrict__ sd,
                                            float* __restrict__ mo, int stride) {
    int i = blockIdx.x;
    int beg = eoff[i], end = eoff[i + 1];
    __shared__ float rb_l[8][9];
    __shared__ float sd_l[8][33];
    int t = threadIdx.x;
    int n = t >> 5, c = t & 31;
    float acc = 0.f;
    for (int base = beg; base < end; base += 8) {
        int j = t >> 5, cc = t & 31;
        int p = base + j;
        float v = 0.f;
        if (p < end) {
            float4 ep = epay[p];
            int di = __float_as_int(ep.z);
            v = sd[di * 32 + cc];
        }
        sd_l[j][cc] = v;
        if (t < 64) {
            int jj = t >> 3, nn = t & 7;
            int pp = base + jj;
            float r = 0.f;
            if (pp < end) {
                float4 ep = epay[pp];
                float d = ep.x, s = ep.y;
                r = 0.6324555320f * __sinf((nn + 1) * 0.6283185307f * d) / d * s;
            }
            rb_l[jj][nn] = r;
        }
        __syncthreads();
#pragma unroll
        for (int j2 = 0; j2 < 8; j2++) acc += rb_l[j2][n] * sd_l[j2][c];
        __syncthreads();
    }
    mo[(size_t)i * stride + t] = acc;
}

// ------------------------------------------------------------------
// ami: per-atom segment of tpay (sequential), 8 triplets/iter
// ------------------------------------------------------------------
__global__ __launch_bounds__(64) void k_ami(const int* __restrict__ toff,
                                            const float4* __restrict__ tpay,
                                            const float* __restrict__ da,
                                            float* __restrict__ ao, int stride) {
    int i = blockIdx.x;
    int beg = toff[i], end = toff[i + 1];
    __shared__ float dij_l[8][9];
    __shared__ float xa_l[8][6];
    int t = threadIdx.x;
    int n = t >> 3, c = t & 7;
    float acc = 0.f;
    for (int base = beg; base < end; base += 8) {
        int j = t >> 3, k = t & 7;
        int p = base + j;
        float v = 0.f, th = 0.f;
        if (p < end) {
            float4 tp = tpay[p];
            int ea = __float_as_int(tp.y), eb = __float_as_int(tp.z);
            v = da[ea * 8 + k] * da[eb * 8 + k];
            th = tp.x;
        }
        dij_l[j][k] = v;
        if (k < 5) xa_l[j][k] = __cosf((float)k * th);
        __syncthreads();
        if (t < 40) {
#pragma unroll
            for (int j2 = 0; j2 < 8; j2++) acc += xa_l[j2][n] * dij_l[j2][c];
        }
        __syncthreads();
    }
    if (t < 40) ao[(size_t)i * stride + t] = acc;
}

// ------------------------------------------------------------------
// MFMA GEMM: dxi = tssr2(ei @ W + b)
// block = 256 thr (4 waves) = 32 atoms x 256 cols; wave w -> cols [64w,64w+64)
// K-chunks of 32; A staged via LDS in fragment order (bf16); B = Wf global.
// ------------------------------------------------------------------
template <int LAYER>
__global__ __launch_bounds__(256) void k_gemm(const float* __restrict__ ei,
                                              const bf8* __restrict__ Wf,
                                              const float* __restrict__ bias,
                                              const float* __restrict__ skip,
                                              float* __restrict__ out) {
    constexpr int DINP = (LAYER == 0) ? DINP0 : DINP1;
    constexpr int NCH = DINP / 32;
    __shared__ __align__(16) __bf16 Asg[2][64][8];  // [tileA][lane][j]
    int t = threadIdx.x;
    int w = t >> 6, lane = t & 63;
    int a0 = blockIdx.x * 32;

    // A staging assignment: 4 bf16 per thread
    int f  = t * 4;
    int tA = f >> 9;
    int al = (f >> 3) & 63;
    int j0 = f & 7;
    int sm = al & 15, sq = al >> 4;
    int ga = a0 + tA * 16 + sm;
    const float* arow = &ei[(size_t)ga * DINP + sq * 8 + j0];
    __bf16* adst = &Asg[0][0][0] + f;
    bool aok = (ga < N_ATOMS);

    f4 acc[2][4];
#pragma unroll
    for (int i = 0; i < 2; i++)
#pragma unroll
        for (int j = 0; j < 4; j++) {
            f4 z = {0.f, 0.f, 0.f, 0.f};
            acc[i][j] = z;
        }

    for (int ch = 0; ch < NCH; ch++) {
        float4 v = make_float4(0.f, 0.f, 0.f, 0.f);
        if (aok) v = *(const float4*)(arow + ch * 32);
        __syncthreads();  // previous chunk's frag reads done
        adst[0] = (__bf16)v.x; adst[1] = (__bf16)v.y;
        adst[2] = (__bf16)v.z; adst[3] = (__bf16)v.w;
        __syncthreads();
        bf8 afr0 = *(const bf8*)&Asg[0][lane][0];
        bf8 afr1 = *(const bf8*)&Asg[1][lane][0];
        const bf8* wp = &Wf[(ch * 16 + w * 4) * 64 + lane];
#pragma unroll
        for (int tn = 0; tn < 4; tn++) {
            bf8 b = wp[tn * 64];
            acc[0][tn] = __builtin_amdgcn_mfma_f32_16x16x32_bf16(afr0, b, acc[0][tn], 0, 0, 0);
            acc[1][tn] = __builtin_amdgcn_mfma_f32_16x16x32_bf16(afr1, b, acc[1][tn], 0, 0, 0);
        }
    }

    // epilogue: C/D layout col = lane&15, row = (lane>>4)*4 + reg
    int nlo = lane & 15, q = lane >> 4;
#pragma unroll
    for (int tA2 = 0; tA2 < 2; tA2++) {
#pragma unroll
        for (int r = 0; r < 4; r++) {
            int atom = a0 + tA2 * 16 + q * 4 + r;
            if (atom < N_ATOMS) {
#pragma unroll
                for (int tn = 0; tn < 4; tn++) {
                    int col = w * 64 + tn * 16 + nlo;
                    float vv = tssr2f(acc[tA2][tn][r] + bias[col]);
                    if (LAYER == 0) {
                        out[(size_t)atom * DINP1 + col] = vv;
                    } else {
                        out[(size_t)atom * 256 + col] = vv + skip[(size_t)atom * DINP1 + col];
                    }
                }
            }
        }
    }
}

// ------------------------------------------------------------------
extern "C" void kernel_launch(void* const* d_in, const int* in_sizes, int n_in,
                              void* d_out, int out_size, void* d_ws, size_t ws_size,
                              hipStream_t stream) {
    const int*   species     = (const int*)d_in[0];
    const int*   edge_src    = (const int*)d_in[1];
    const int*   edge_dst    = (const int*)d_in[2];
    const float* distances   = (const float*)d_in[3];
    const float* sw          = (const float*)d_in[4];
    const float* angles      = (const float*)d_in[5];
    const int*   angle_src   = (const int*)d_in[6];
    const int*   angle_dst   = (const int*)d_in[7];
    const int*   central     = (const int*)d_in[8];
    const float* dist_a      = (const float*)d_in[9];
    const float* sw_a        = (const float*)d_in[10];
    const float* table       = (const float*)d_in[11];
    const float* W_si0       = (const float*)d_in[12];
    const float* W_si1       = (const float*)d_in[13];
    const float* W_da0       = (const float*)d_in[14];
    const float* W_da1       = (const float*)d_in[15];
    const float* W_mix0      = (const float*)d_in[16];
    const float* b_mix0      = (const float*)d_in[17];
    const float* W_mix1      = (const float*)d_in[18];
    const float* b_mix1      = (const float*)d_in[19];
    float* out = (float*)d_out;

    char* p = (char*)d_ws;
    auto alloc = [&](size_t bytes) {
        char* r = p;
        p += (bytes + 255) & ~(size_t)255;
        return (void*)r;
    };
    float*  ei0  = (float*)alloc((size_t)N_ATOMS * DINP0 * 4);
    float*  ei1  = (float*)alloc((size_t)N_ATOMS * DINP1 * 4);
    float*  sd   = (float*)alloc((size_t)N_ATOMS * 32 * 4);
    float*  da   = (float*)alloc((size_t)NEA * 8 * 4);
    float4* epay = (float4*)alloc((size_t)NE * 16);
    float4* tpay = (float4*)alloc((size_t)NT * 16);
    bf8*    Wf0  = (bf8*)alloc((size_t)(DINP0 / 32) * 16 * 64 * 16);
    bf8*    Wf1  = (bf8*)alloc((size_t)(DINP1 / 32) * 16 * 64 * 16);
    int* ecnt = (int*)alloc((size_t)N_ATOMS * 4);
    int* eoff = (int*)alloc((size_t)(N_ATOMS + 1) * 4);
    int* tcnt = (int*)alloc((size_t)N_ATOMS * 4);
    int* toff = (int*)alloc((size_t)(N_ATOMS + 1) * 4);
    int* gce  = (int*)alloc((size_t)NBUK * 4);
    int* gct  = (int*)alloc((size_t)NBUK * 4);
    (void)ws_size;

    // bucket staging arrays alias ei1 (written only later)
    float4* tbuk = (float4*)ei1;
    float4* ebuk = (float4*)((char*)ei1 + (size_t)NT * 16);

    hipMemsetAsync(ecnt, 0, (size_t)N_ATOMS * 4, stream);
    hipMemsetAsync(tcnt, 0, (size_t)N_ATOMS * 4, stream);

    int nfrag0 = (DINP0 / 32) * 16 * 64;
    int nfrag1 = (DINP1 / 32) * 16 * 64;
    k_wprep<<<(nfrag0 + 255) / 256, 256, 0, stream>>>(W_mix0, Wf0, DIN0, nfrag0);
    k_wprep<<<(nfrag1 + 255) / 256, 256, 0, stream>>>(W_mix1, Wf1, DIN1, nfrag1);

    int nct = NE + NT;
    k_count<<<(nct + 255) / 256, 256, 0, stream>>>(edge_src, central, ecnt, tcnt);
    k_scan<<<2, 1024, 0, stream>>>(ecnt, eoff, tcnt, toff, N_ATOMS);
    k_initcur<<<(NBUK + 255) / 256, 256, 0, stream>>>(eoff, toff, gce, gct);

    k_binA<true><<<(NE + 4095) / 4096, 512, 0, stream>>>(
        distances, sw, nullptr, edge_dst, edge_src, gce, ebuk, NE);
    k_binA<false><<<(NT + 4095) / 4096, 512, 0, stream>>>(
        angles, nullptr, angle_src, angle_dst, central, gct, tbuk, NT);
    k_binB<<<NBUK, 256, 0, stream>>>(eoff, ebuk, epay);
    k_binB<<<NBUK, 256, 0, stream>>>(toff, tbuk, tpay);

    int gemm_grid = (N_ATOMS + 31) / 32;

    // ---- layer 0 ----
    k_s0<<<(N_ATOMS * 120 + 255) / 256, 256, 0, stream>>>(species, table, W_si0, ei0, sd);
    k_da<<<(NEA + 255) / 256, 256, 0, stream>>>(dist_a, sw_a, W_da0, da);
    k_mi<<<N_ATOMS, 256, 0, stream>>>(eoff, epay, sd, ei0 + 80, DINP0);
    k_ami<<<N_ATOMS, 64, 0, stream>>>(toff, tpay, da, ei0 + 336, DINP0);
    k_gemm<0><<<gemm_grid, 256, 0, stream>>>(ei0, Wf0, b_mix0, nullptr, ei1);

    // ---- layer 1 ----
    k_s1<<<N_ATOMS, 128, 0, stream>>>(ei1, W_si1, sd);
    k_da<<<(NEA + 255) / 256, 256, 0, stream>>>(dist_a, sw_a, W_da1, da);
    k_mi<<<N_ATOMS, 256, 0, stream>>>(eoff, epay, sd, ei1 + 320, DINP1);
    k_ami<<<N_ATOMS, 64, 0, stream>>>(toff, tpay, da, ei1 + 576, DINP1);
    k_gemm<1><<<gemm_grid, 256, 0, stream>>>(ei1, Wf1, b_mix1, ei1, out);
}

// Round 7
// 614.207 us; speedup vs baseline: 2.9514x; 1.2248x over previous
//
#include <hip/hip_runtime.h>
#include <hip/hip_bf16.h>

typedef __hip_bfloat16 bf16;
typedef __bf16 bf8 __attribute__((ext_vector_type(8)));
typedef float  f4  __attribute__((ext_vector_type(4)));

#define N_ATOMS 25000
#define NE      800000
#define NEA     300000
#define NT      1600000
#define APB     64
#define NBUK    ((N_ATOMS + APB - 1) / APB)   // 391

#define DIN0  376   // 16 xi + 64 si + 256 mi + 40 ami
#define DIN1  616   // 256 xi + 64 si + 256 mi + 40 ami
#define DINP0 384   // padded (mult of 32)
#define DINP1 640

#define EBLK ((NE + 4095) / 4096)   // 196

__device__ __forceinline__ float tssr2f(float x) {
    float ax = fabsf(x);
    return (ax <= 1.f) ? x : copysignf(2.f * __builtin_sqrtf(ax) - 1.f, x);
}

// ------------------------------------------------------------------
// Bucket-granularity count: per-block LDS histogram, one flush per block.
// Avoids per-element global atomics (74 MB HBM write in round 5's k_count).
// ------------------------------------------------------------------
__global__ __launch_bounds__(256) void k_bcount(const int* __restrict__ esrc,
                                                const int* __restrict__ cat,
                                                int* __restrict__ ebcnt,
                                                int* __restrict__ tbcnt) {
    __shared__ int h[NBUK];
    int t = threadIdx.x;
    for (int b = t; b < NBUK; b += 256) h[b] = 0;
    __syncthreads();
    bool isE = blockIdx.x < EBLK;
    const int* key = isE ? esrc : cat;
    int n = isE ? NE : NT;
    int base = (isE ? blockIdx.x : (blockIdx.x - EBLK)) * 4096;
#pragma unroll
    for (int k = 0; k < 16; k++) {
        int idx = base + k * 256 + t;
        if (idx < n) atomicAdd(&h[key[idx] >> 6], 1);
    }
    __syncthreads();
    int* g = isE ? ebcnt : tbcnt;
    for (int b = t; b < NBUK; b += 256)
        if (h[b]) atomicAdd(&g[b], h[b]);
}

// ------------------------------------------------------------------
// Scan 391 bucket counts -> bucket offsets (+reservation cursors).
// block 0: edges, block 1: triplets.
// ------------------------------------------------------------------
__global__ __launch_bounds__(512) void k_scanB(const int* cnt0, int* off0, int* cur0,
                                               int* aoff0,
                                               const int* cnt1, int* off1, int* cur1,
                                               int* aoff1) {
    const int* cnt = blockIdx.x ? cnt1 : cnt0;
    int* off  = blockIdx.x ? off1 : off0;
    int* cur  = blockIdx.x ? cur1 : cur0;
    int* aoff = blockIdx.x ? aoff1 : aoff0;
    int nelem = blockIdx.x ? NT : NE;
    __shared__ int sh[512];
    int t = threadIdx.x;
    int v = (t < NBUK) ? cnt[t] : 0;
    sh[t] = v;
    __syncthreads();
    for (int d = 1; d < 512; d <<= 1) {
        int a = (t >= d) ? sh[t - d] : 0;
        __syncthreads();
        sh[t] += a;
        __syncthreads();
    }
    int excl = sh[t] - v;
    if (t <= NBUK) { off[t] = excl; if (t < NBUK) cur[t] = excl; }
    if (t == 0) aoff[N_ATOMS] = nelem;
}

// ------------------------------------------------------------------
// Phase A: bin payloads into coarse buckets (bucket = key >> 6)
// ------------------------------------------------------------------
template <bool EDGE>
__global__ __launch_bounds__(512) void k_binA(const float* __restrict__ fA,
                                              const float* __restrict__ fB,
                                              const int* __restrict__ iB,
                                              const int* __restrict__ iC,
                                              const int* __restrict__ key,
                                              int* __restrict__ gcur,
                                              float4* __restrict__ buk, int n) {
    __shared__ int cnt[NBUK];
    __shared__ int rbase[NBUK];
    int t = threadIdx.x;
    for (int b = t; b < NBUK; b += 512) cnt[b] = 0;
    __syncthreads();
    int base = blockIdx.x * 4096;
    float4 pay[8];
    int bk[8], off[8];
#pragma unroll
    for (int k = 0; k < 8; k++) {
        int idx = base + k * 512 + t;
        bk[k] = -1;
        if (idx < n) {
            float4 p;
            p.x = fA[idx];
            p.y = EDGE ? fB[idx] : __int_as_float(iB[idx]);
            p.z = __int_as_float(iC[idx]);
            int ky = key[idx];
            p.w = __int_as_float(ky);
            pay[k] = p;
            bk[k] = ky >> 6;
            off[k] = atomicAdd(&cnt[bk[k]], 1);
        }
    }
    __syncthreads();
    for (int b = t; b < NBUK; b += 512)
        if (cnt[b]) rbase[b] = atomicAdd(&gcur[b], cnt[b]);
    __syncthreads();
#pragma unroll
    for (int k = 0; k < 8; k++)
        if (bk[k] >= 0) buk[rbase[bk[k]] + off[k]] = pay[k];
}

// ------------------------------------------------------------------
// Phase B: one workgroup per bucket; derives per-atom CSR offsets in LDS
// (writes aoff) and places payloads at exact slots.
// ------------------------------------------------------------------
__global__ __launch_bounds__(256) void k_binB(const int* __restrict__ bkoff,
                                              const float4* __restrict__ buk,
                                              float4* __restrict__ fin,
                                              int* __restrict__ aoff) {
    int b = blockIdx.x;
    int lo = b * APB;
    int hi = min(lo + APB, N_ATOMS);
    __shared__ int cnt[APB];
    __shared__ int cur[APB];
    int t = threadIdx.x;
    if (t < APB) cnt[t] = 0;
    __syncthreads();
    int pbeg = bkoff[b], pend = bkoff[b + 1];
    for (int p = pbeg + t; p < pend; p += 256) {
        int a = __float_as_int(((const float*)(buk + p))[3]);
        atomicAdd(&cnt[a - lo], 1);
    }
    __syncthreads();
    if (t == 0) {
        int run = pbeg;
        for (int k = 0; k < hi - lo; k++) {
            cur[k] = run;
            aoff[lo + k] = run;
            run += cnt[k];
        }
    }
    __syncthreads();
    for (int p = pbeg + t; p < pend; p += 256) {
        float4 pay = buk[p];
        int a = __float_as_int(pay.w);
        int slot = atomicAdd(&cur[a - lo], 1);
        fin[slot] = pay;
    }
}

// ------------------------------------------------------------------
// W -> bf16 fragment layout: frag f = (chunk*16 + ctile)*64 + lane
// ------------------------------------------------------------------
__global__ void k_wprep(const float* __restrict__ W, bf8* __restrict__ Wf,
                        int DIN, int nfrag) {
    int f = blockIdx.x * blockDim.x + threadIdx.x;
    if (f >= nfrag) return;
    int lane = f & 63;
    int tile = (f >> 6) & 15;
    int chunk = f >> 10;
    int n = tile * 16 + (lane & 15);
    int kb = chunk * 32 + (lane >> 4) * 8;
    bf8 v;
#pragma unroll
    for (int j = 0; j < 8; j++) {
        int k = kb + j;
        v[j] = (__bf16)((k < DIN) ? W[k * 256 + n] : 0.f);
    }
    Wf[f] = v;
}

// ------------------------------------------------------------------
// layer 0: ei0[:,0:16) = table[sp]; s = table[sp] @ W_si0 (16x96); pad zeros
// ------------------------------------------------------------------
__global__ void k_s0(const int* __restrict__ sp, const float* __restrict__ table,
                     const float* __restrict__ W, float* __restrict__ ei0,
                     float* __restrict__ sd) {
    int idx = blockIdx.x * blockDim.x + threadIdx.x;
    if (idx >= N_ATOMS * 120) return;
    int i = idx / 120;
    int c = idx - i * 120;
    if (c >= 112) {
        ei0[(size_t)i * DINP0 + 376 + (c - 112)] = 0.f;
        return;
    }
    int s = sp[i];
    if (c < 16) {
        ei0[(size_t)i * DINP0 + c] = table[s * 16 + c];
    } else {
        int cc = c - 16;
        float acc = 0.f;
#pragma unroll
        for (int k = 0; k < 16; k++)
            acc += table[s * 16 + k] * W[k * 96 + cc];
        if (cc < 64) ei0[(size_t)i * DINP0 + 16 + cc] = acc;
        else         sd[i * 32 + cc - 64]             = acc;
    }
}

// layer 1: xi = ei1[:,0:256); s = xi @ W_si1 (256x96); pad zeros
__global__ __launch_bounds__(128) void k_s1(float* __restrict__ ei1,
                                            const float* __restrict__ W,
                                            float* __restrict__ sd) {
    int i = blockIdx.x;
    __shared__ float x[256];
    for (int k = threadIdx.x; k < 256; k += 128) x[k] = ei1[(size_t)i * DINP1 + k];
    __syncthreads();
    int c = threadIdx.x;
    if (c < 96) {
        float acc = 0.f;
#pragma unroll 8
        for (int k = 0; k < 256; k++)
            acc += x[k] * W[k * 96 + c];
        if (c < 64) ei1[(size_t)i * DINP1 + 256 + c] = acc;
        else        sd[i * 32 + c - 64]              = acc;
    } else if (c < 120) {
        ei1[(size_t)i * DINP1 + 616 + (c - 96)] = 0.f;
    }
}

// ------------------------------------------------------------------
// da = (bessel(dist_angle)*switch_angle) @ W_da   -> EA x 8 fp32
// ------------------------------------------------------------------
__global__ void k_da(const float* __restrict__ dist, const float* __restrict__ sw,
                     const float* __restrict__ W, float* __restrict__ da) {
    int e = blockIdx.x * blockDim.x + threadIdx.x;
    if (e >= NEA) return;
    float d = dist[e];
    float s = sw[e];
    float rb[8];
#pragma unroll
    for (int n = 0; n < 8; n++)
        rb[n] = 0.7559289460f * __sinf((n + 1) * 0.8975979010f * d) / d * s;
    float w[8];
#pragma unroll
    for (int c = 0; c < 8; c++) {
        float acc = 0.f;
#pragma unroll
        for (int n = 0; n < 8; n++) acc += rb[n] * W[n * 8 + c];
        w[c] = acc;
    }
#pragma unroll
    for (int c = 0; c < 8; c++) da[e * 8 + c] = w[c];
}

// ------------------------------------------------------------------
// mi: per-atom segment of epay (sequential), 8 edges/iter
// ------------------------------------------------------------------
__global__ __launch_bounds__(256) void k_mi(const int* __restrict__ eoff,
                                            const float4* __restrict__ epay,
                                            const float* __restrict__ sd,
                                            float* __restrict__ mo, int stride) {
    int i = blockIdx.x;
    int beg = eoff[i], end = eoff[i + 1];
    __shared__ float rb_l[8][9];
    __shared__ float sd_l[8][33];
    int t = threadIdx.x;
    int n = t >> 5, c = t & 31;
    float acc = 0.f;
    for (int base = beg; base < end; base += 8) {
        int j = t >> 5, cc = t & 31;
        int p = base + j;
        float v = 0.f;
        if (p < end) {
            float4 ep = epay[p];
            int di = __float_as_int(ep.z);
            v = sd[di * 32 + cc];
        }
        sd_l[j][cc] = v;
        if (t < 64) {
            int jj = t >> 3, nn = t & 7;
            int pp = base + jj;
            float r = 0.f;
            if (pp < end) {
                float4 ep = epay[pp];
                float d = ep.x, s = ep.y;
                r = 0.6324555320f * __sinf((nn + 1) * 0.6283185307f * d) / d * s;
            }
            rb_l[jj][nn] = r;
        }
        __syncthreads();
#pragma unroll
        for (int j2 = 0; j2 < 8; j2++) acc += rb_l[j2][n] * sd_l[j2][c];
        __syncthreads();
    }
    mo[(size_t)i * stride + t] = acc;
}

// ------------------------------------------------------------------
// ami: per-atom segment of tpay (sequential), 8 triplets/iter
// ------------------------------------------------------------------
__global__ __launch_bounds__(64) void k_ami(const int* __restrict__ toff,
                                            const float4* __restrict__ tpay,
                                            const float* __restrict__ da,
                                            float* __restrict__ ao, int stride) {
    int i = blockIdx.x;
    int beg = toff[i], end = toff[i + 1];
    __shared__ float dij_l[8][9];
    __shared__ float xa_l[8][6];
    int t = threadIdx.x;
    int n = t >> 3, c = t & 7;
    float acc = 0.f;
    for (int base = beg; base < end; base += 8) {
        int j = t >> 3, k = t & 7;
        int p = base + j;
        float v = 0.f, th = 0.f;
        if (p < end) {
            float4 tp = tpay[p];
            int ea = __float_as_int(tp.y), eb = __float_as_int(tp.z);
            v = da[ea * 8 + k] * da[eb * 8 + k];
            th = tp.x;
        }
        dij_l[j][k] = v;
        if (k < 5) xa_l[j][k] = __cosf((float)k * th);
        __syncthreads();
        if (t < 40) {
#pragma unroll
            for (int j2 = 0; j2 < 8; j2++) acc += xa_l[j2][n] * dij_l[j2][c];
        }
        __syncthreads();
    }
    if (t < 40) ao[(size_t)i * stride + t] = acc;
}

// ------------------------------------------------------------------
// MFMA GEMM: dxi = tssr2(ei @ W + b)
// ------------------------------------------------------------------
template <int LAYER>
__global__ __launch_bounds__(256) void k_gemm(const float* __restrict__ ei,
                                              const bf8* __restrict__ Wf,
                                              const float* __restrict__ bias,
                                              const float* __restrict__ skip,
                                              float* __restrict__ out) {
    constexpr int DINP = (LAYER == 0) ? DINP0 : DINP1;
    constexpr int NCH = DINP / 32;
    __shared__ __align__(16) __bf16 Asg[2][64][8];
    int t = threadIdx.x;
    int w = t >> 6, lane = t & 63;
    int a0 = blockIdx.x * 32;

    int f  = t * 4;
    int tA = f >> 9;
    int al = (f >> 3) & 63;
    int j0 = f & 7;
    int sm = al & 15, sq = al >> 4;
    int ga = a0 + tA * 16 + sm;
    const float* arow = &ei[(size_t)ga * DINP + sq * 8 + j0];
    __bf16* adst = &Asg[0][0][0] + f;
    bool aok = (ga < N_ATOMS);

    f4 acc[2][4];
#pragma unroll
    for (int i = 0; i < 2; i++)
#pragma unroll
        for (int j = 0; j < 4; j++) {
            f4 z = {0.f, 0.f, 0.f, 0.f};
            acc[i][j] = z;
        }

    for (int ch = 0; ch < NCH; ch++) {
        float4 v = make_float4(0.f, 0.f, 0.f, 0.f);
        if (aok) v = *(const float4*)(arow + ch * 32);
        __syncthreads();
        adst[0] = (__bf16)v.x; adst[1] = (__bf16)v.y;
        adst[2] = (__bf16)v.z; adst[3] = (__bf16)v.w;
        __syncthreads();
        bf8 afr0 = *(const bf8*)&Asg[0][lane][0];
        bf8 afr1 = *(const bf8*)&Asg[1][lane][0];
        const bf8* wp = &Wf[(ch * 16 + w * 4) * 64 + lane];
#pragma unroll
        for (int tn = 0; tn < 4; tn++) {
            bf8 b = wp[tn * 64];
            acc[0][tn] = __builtin_amdgcn_mfma_f32_16x16x32_bf16(afr0, b, acc[0][tn], 0, 0, 0);
            acc[1][tn] = __builtin_amdgcn_mfma_f32_16x16x32_bf16(afr1, b, acc[1][tn], 0, 0, 0);
        }
    }

    int nlo = lane & 15, q = lane >> 4;
#pragma unroll
    for (int tA2 = 0; tA2 < 2; tA2++) {
#pragma unroll
        for (int r = 0; r < 4; r++) {
            int atom = a0 + tA2 * 16 + q * 4 + r;
            if (atom < N_ATOMS) {
#pragma unroll
                for (int tn = 0; tn < 4; tn++) {
                    int col = w * 64 + tn * 16 + nlo;
                    float vv = tssr2f(acc[tA2][tn][r] + bias[col]);
                    if (LAYER == 0) {
                        out[(size_t)atom * DINP1 + col] = vv;
                    } else {
                        out[(size_t)atom * 256 + col] = vv + skip[(size_t)atom * DINP1 + col];
                    }
                }
            }
        }
    }
}

// ------------------------------------------------------------------
extern "C" void kernel_launch(void* const* d_in, const int* in_sizes, int n_in,
                              void* d_out, int out_size, void* d_ws, size_t ws_size,
                              hipStream_t stream) {
    const int*   species     = (const int*)d_in[0];
    const int*   edge_src    = (const int*)d_in[1];
    const int*   edge_dst    = (const int*)d_in[2];
    const float* distances   = (const float*)d_in[3];
    const float* sw          = (const float*)d_in[4];
    const float* angles      = (const float*)d_in[5];
    const int*   angle_src   = (const int*)d_in[6];
    const int*   angle_dst   = (const int*)d_in[7];
    const int*   central     = (const int*)d_in[8];
    const float* dist_a      = (const float*)d_in[9];
    const float* sw_a        = (const float*)d_in[10];
    const float* table       = (const float*)d_in[11];
    const float* W_si0       = (const float*)d_in[12];
    const float* W_si1       = (const float*)d_in[13];
    const float* W_da0       = (const float*)d_in[14];
    const float* W_da1       = (const float*)d_in[15];
    const float* W_mix0      = (const float*)d_in[16];
    const float* b_mix0      = (const float*)d_in[17];
    const float* W_mix1      = (const float*)d_in[18];
    const float* b_mix1      = (const float*)d_in[19];
    float* out = (float*)d_out;

    char* p = (char*)d_ws;
    auto alloc = [&](size_t bytes) {
        char* r = p;
        p += (bytes + 255) & ~(size_t)255;
        return (void*)r;
    };
    float*  ei0  = (float*)alloc((size_t)N_ATOMS * DINP0 * 4);
    float*  ei1  = (float*)alloc((size_t)N_ATOMS * DINP1 * 4);
    float*  sd   = (float*)alloc((size_t)N_ATOMS * 32 * 4);
    float*  da   = (float*)alloc((size_t)NEA * 8 * 4);
    float4* epay = (float4*)alloc((size_t)NE * 16);
    float4* tpay = (float4*)alloc((size_t)NT * 16);
    bf8*    Wf0  = (bf8*)alloc((size_t)(DINP0 / 32) * 16 * 64 * 16);
    bf8*    Wf1  = (bf8*)alloc((size_t)(DINP1 / 32) * 16 * 64 * 16);
    int* eoff   = (int*)alloc((size_t)(N_ATOMS + 1) * 4);
    int* toff   = (int*)alloc((size_t)(N_ATOMS + 1) * 4);
    int* ebcnt  = (int*)alloc((size_t)NBUK * 4);
    int* tbcnt  = (int*)alloc((size_t)NBUK * 4);
    int* ebkoff = (int*)alloc((size_t)(NBUK + 1) * 4);
    int* tbkoff = (int*)alloc((size_t)(NBUK + 1) * 4);
    int* gce    = (int*)alloc((size_t)NBUK * 4);
    int* gct    = (int*)alloc((size_t)NBUK * 4);
    (void)ws_size;

    // bucket staging arrays alias ei1 (written only later by k_gemm<0>)
    float4* tbuk = (float4*)ei1;
    float4* ebuk = (float4*)((char*)ei1 + (size_t)NT * 16);

    hipMemsetAsync(ebcnt, 0, (size_t)NBUK * 4, stream);
    hipMemsetAsync(tbcnt, 0, (size_t)NBUK * 4, stream);

    int nfrag0 = (DINP0 / 32) * 16 * 64;
    int nfrag1 = (DINP1 / 32) * 16 * 64;
    k_wprep<<<(nfrag0 + 255) / 256, 256, 0, stream>>>(W_mix0, Wf0, DIN0, nfrag0);
    k_wprep<<<(nfrag1 + 255) / 256, 256, 0, stream>>>(W_mix1, Wf1, DIN1, nfrag1);

    k_bcount<<<EBLK + (NT + 4095) / 4096, 256, 0, stream>>>(edge_src, central, ebcnt, tbcnt);
    k_scanB<<<2, 512, 0, stream>>>(ebcnt, ebkoff, gce, eoff, tbcnt, tbkoff, gct, toff);

    k_binA<true><<<(NE + 4095) / 4096, 512, 0, stream>>>(
        distances, sw, nullptr, edge_dst, edge_src, gce, ebuk, NE);
    k_binA<false><<<(NT + 4095) / 4096, 512, 0, stream>>>(
        angles, nullptr, angle_src, angle_dst, central, gct, tbuk, NT);
    k_binB<<<NBUK, 256, 0, stream>>>(ebkoff, ebuk, epay, eoff);
    k_binB<<<NBUK, 256, 0, stream>>>(tbkoff, tbuk, tpay, toff);

    int gemm_grid = (N_ATOMS + 31) / 32;

    // ---- layer 0 ----
    k_s0<<<(N_ATOMS * 120 + 255) / 256, 256, 0, stream>>>(species, table, W_si0, ei0, sd);
    k_da<<<(NEA + 255) / 256, 256, 0, stream>>>(dist_a, sw_a, W_da0, da);
    k_mi<<<N_ATOMS, 256, 0, stream>>>(eoff, epay, sd, ei0 + 80, DINP0);
    k_ami<<<N_ATOMS, 64, 0, stream>>>(toff, tpay, da, ei0 + 336, DINP0);
    k_gemm<0><<<gemm_grid, 256, 0, stream>>>(ei0, Wf0, b_mix0, nullptr, ei1);

    // ---- layer 1 ----
    k_s1<<<N_ATOMS, 128, 0, stream>>>(ei1, W_si1, sd);
    k_da<<<(NEA + 255) / 256, 256, 0, stream>>>(dist_a, sw_a, W_da1, da);
    k_mi<<<N_ATOMS, 256, 0, stream>>>(eoff, epay, sd, ei1 + 320, DINP1);
    k_ami<<<N_ATOMS, 64, 0, stream>>>(toff, tpay, da, ei1 + 576, DINP1);
    k_gemm<1><<<gemm_grid, 256, 0, stream>>>(ei1, Wf1, b_mix1, ei1, out);
}

// Round 8
// 540.951 us; speedup vs baseline: 3.3511x; 1.1354x over previous
//
#include <hip/hip_runtime.h>
#include <hip/hip_bf16.h>

typedef __hip_bfloat16 bf16;
typedef __bf16 bf8 __attribute__((ext_vector_type(8)));
typedef float  f4  __attribute__((ext_vector_type(4)));

#define N_ATOMS 25000
#define NE      800000
#define NEA     300000
#define NT      1600000
#define APB     64
#define NBUK    ((N_ATOMS + APB - 1) / APB)   // 391

#define DIN0  376   // 16 xi + 64 si + 256 mi + 40 ami
#define DIN1  616   // 256 xi + 64 si + 256 mi + 40 ami
#define DINP0 384   // padded (mult of 32)
#define DINP1 640

#define EBLK ((NE + 4095) / 4096)   // 196

__device__ __forceinline__ float tssr2f(float x) {
    float ax = fabsf(x);
    return (ax <= 1.f) ? x : copysignf(2.f * __builtin_sqrtf(ax) - 1.f, x);
}

// ------------------------------------------------------------------
// Bucket-granularity count: per-block LDS histogram, one flush per block.
// ------------------------------------------------------------------
__global__ __launch_bounds__(256) void k_bcount(const int* __restrict__ esrc,
                                                const int* __restrict__ cat,
                                                int* __restrict__ ebcnt,
                                                int* __restrict__ tbcnt) {
    __shared__ int h[NBUK];
    int t = threadIdx.x;
    for (int b = t; b < NBUK; b += 256) h[b] = 0;
    __syncthreads();
    bool isE = blockIdx.x < EBLK;
    const int* key = isE ? esrc : cat;
    int n = isE ? NE : NT;
    int base = (isE ? blockIdx.x : (blockIdx.x - EBLK)) * 4096;
#pragma unroll
    for (int k = 0; k < 16; k++) {
        int idx = base + k * 256 + t;
        if (idx < n) atomicAdd(&h[key[idx] >> 6], 1);
    }
    __syncthreads();
    int* g = isE ? ebcnt : tbcnt;
    for (int b = t; b < NBUK; b += 256)
        if (h[b]) atomicAdd(&g[b], h[b]);
}

// ------------------------------------------------------------------
// Scan 391 bucket counts -> bucket offsets (+reservation cursors).
// ------------------------------------------------------------------
__global__ __launch_bounds__(512) void k_scanB(const int* cnt0, int* off0, int* cur0,
                                               int* aoff0,
                                               const int* cnt1, int* off1, int* cur1,
                                               int* aoff1) {
    const int* cnt = blockIdx.x ? cnt1 : cnt0;
    int* off  = blockIdx.x ? off1 : off0;
    int* cur  = blockIdx.x ? cur1 : cur0;
    int* aoff = blockIdx.x ? aoff1 : aoff0;
    int nelem = blockIdx.x ? NT : NE;
    __shared__ int sh[512];
    int t = threadIdx.x;
    int v = (t < NBUK) ? cnt[t] : 0;
    sh[t] = v;
    __syncthreads();
    for (int d = 1; d < 512; d <<= 1) {
        int a = (t >= d) ? sh[t - d] : 0;
        __syncthreads();
        sh[t] += a;
        __syncthreads();
    }
    int excl = sh[t] - v;
    if (t <= NBUK) { off[t] = excl; if (t < NBUK) cur[t] = excl; }
    if (t == 0) aoff[N_ATOMS] = nelem;
}

// ------------------------------------------------------------------
// Phase A: bin payloads into coarse buckets (bucket = key >> 6)
// ------------------------------------------------------------------
template <bool EDGE>
__global__ __launch_bounds__(512) void k_binA(const float* __restrict__ fA,
                                              const float* __restrict__ fB,
                                              const int* __restrict__ iB,
                                              const int* __restrict__ iC,
                                              const int* __restrict__ key,
                                              int* __restrict__ gcur,
                                              float4* __restrict__ buk, int n) {
    __shared__ int cnt[NBUK];
    __shared__ int rbase[NBUK];
    int t = threadIdx.x;
    for (int b = t; b < NBUK; b += 512) cnt[b] = 0;
    __syncthreads();
    int base = blockIdx.x * 4096;
    float4 pay[8];
    int bk[8], off[8];
#pragma unroll
    for (int k = 0; k < 8; k++) {
        int idx = base + k * 512 + t;
        bk[k] = -1;
        if (idx < n) {
            float4 p;
            p.x = fA[idx];
            p.y = EDGE ? fB[idx] : __int_as_float(iB[idx]);
            p.z = __int_as_float(iC[idx]);
            int ky = key[idx];
            p.w = __int_as_float(ky);
            pay[k] = p;
            bk[k] = ky >> 6;
            off[k] = atomicAdd(&cnt[bk[k]], 1);
        }
    }
    __syncthreads();
    for (int b = t; b < NBUK; b += 512)
        if (cnt[b]) rbase[b] = atomicAdd(&gcur[b], cnt[b]);
    __syncthreads();
#pragma unroll
    for (int k = 0; k < 8; k++)
        if (bk[k] >= 0) buk[rbase[bk[k]] + off[k]] = pay[k];
}

// ------------------------------------------------------------------
// Phase B: one workgroup per bucket; derives per-atom CSR offsets in LDS
// ------------------------------------------------------------------
__global__ __launch_bounds__(256) void k_binB(const int* __restrict__ bkoff,
                                              const float4* __restrict__ buk,
                                              float4* __restrict__ fin,
                                              int* __restrict__ aoff) {
    int b = blockIdx.x;
    int lo = b * APB;
    int hi = min(lo + APB, N_ATOMS);
    __shared__ int cnt[APB];
    __shared__ int cur[APB];
    int t = threadIdx.x;
    if (t < APB) cnt[t] = 0;
    __syncthreads();
    int pbeg = bkoff[b], pend = bkoff[b + 1];
    for (int p = pbeg + t; p < pend; p += 256) {
        int a = __float_as_int(((const float*)(buk + p))[3]);
        atomicAdd(&cnt[a - lo], 1);
    }
    __syncthreads();
    if (t == 0) {
        int run = pbeg;
        for (int k = 0; k < hi - lo; k++) {
            cur[k] = run;
            aoff[lo + k] = run;
            run += cnt[k];
        }
    }
    __syncthreads();
    for (int p = pbeg + t; p < pend; p += 256) {
        float4 pay = buk[p];
        int a = __float_as_int(pay.w);
        int slot = atomicAdd(&cur[a - lo], 1);
        fin[slot] = pay;
    }
}

// ------------------------------------------------------------------
// W -> bf16 fragment layout (generalized): frag f = (chunk*ntiles + tile)*64 + lane
//   holds W[chunk*32 + (lane>>4)*8 + j][tile*16 + (lane&15)], N = ntiles*16 cols
// ------------------------------------------------------------------
__global__ void k_wprep(const float* __restrict__ W, bf8* __restrict__ Wf,
                        int K, int N, int ntiles, int nfrag) {
    int f = blockIdx.x * blockDim.x + threadIdx.x;
    if (f >= nfrag) return;
    int lane = f & 63;
    int ft = f >> 6;
    int tile = ft % ntiles;
    int chunk = ft / ntiles;
    int n = tile * 16 + (lane & 15);
    int kb = chunk * 32 + (lane >> 4) * 8;
    bf8 v;
#pragma unroll
    for (int j = 0; j < 8; j++) {
        int k = kb + j;
        v[j] = (__bf16)((k < K) ? W[k * N + n] : 0.f);
    }
    Wf[f] = v;
}

// ------------------------------------------------------------------
// layer 0: ei0[:,0:16) = table[sp]; s = table[sp] @ W_si0 (16x96); pad zeros
// ------------------------------------------------------------------
__global__ void k_s0(const int* __restrict__ sp, const float* __restrict__ table,
                     const float* __restrict__ W, float* __restrict__ ei0,
                     float* __restrict__ sd) {
    int idx = blockIdx.x * blockDim.x + threadIdx.x;
    if (idx >= N_ATOMS * 120) return;
    int i = idx / 120;
    int c = idx - i * 120;
    if (c >= 112) {
        ei0[(size_t)i * DINP0 + 376 + (c - 112)] = 0.f;
        return;
    }
    int s = sp[i];
    if (c < 16) {
        ei0[(size_t)i * DINP0 + c] = table[s * 16 + c];
    } else {
        int cc = c - 16;
        float acc = 0.f;
#pragma unroll
        for (int k = 0; k < 16; k++)
            acc += table[s * 16 + k] * W[k * 96 + cc];
        if (cc < 64) ei0[(size_t)i * DINP0 + 16 + cc] = acc;
        else         sd[i * 32 + cc - 64]             = acc;
    }
}

// ------------------------------------------------------------------
// layer 1 s: MFMA GEMM 25000x96 = xi(25000x256) @ W_si1(256x96)
// 4 waves = 64 atoms/block; cols 0..64 -> ei1[:,256..320), 64..96 -> sd;
// also zeroes ei1 pad cols 616..640.
// ------------------------------------------------------------------
__global__ __launch_bounds__(256) void k_s1(const float* __restrict__ ei1,
                                            const bf8* __restrict__ Wf,
                                            float* __restrict__ ei1o,
                                            float* __restrict__ sd) {
    __shared__ __align__(16) __bf16 Asg[4][64][8];
    int t = threadIdx.x;
    int w = t >> 6, lane = t & 63;
    int a0 = blockIdx.x * 64;

    int satom = a0 + (t >> 2);
    int k8 = (t & 3) * 8;
    const float* arow = &ei1[(size_t)satom * DINP1 + k8];
    bool aok = satom < N_ATOMS;
    int dw = (t >> 2) >> 4;
    int dl = ((t >> 2) & 15) | ((t & 3) << 4);
    __bf16* adst = &Asg[dw][dl][0];

    f4 acc[6];
#pragma unroll
    for (int j = 0; j < 6; j++) {
        f4 z = {0.f, 0.f, 0.f, 0.f};
        acc[j] = z;
    }

    for (int ch = 0; ch < 8; ch++) {
        float4 v0 = make_float4(0.f, 0.f, 0.f, 0.f);
        float4 v1 = make_float4(0.f, 0.f, 0.f, 0.f);
        if (aok) {
            v0 = *(const float4*)(arow + ch * 32);
            v1 = *(const float4*)(arow + ch * 32 + 4);
        }
        __syncthreads();
        adst[0] = (__bf16)v0.x; adst[1] = (__bf16)v0.y;
        adst[2] = (__bf16)v0.z; adst[3] = (__bf16)v0.w;
        adst[4] = (__bf16)v1.x; adst[5] = (__bf16)v1.y;
        adst[6] = (__bf16)v1.z; adst[7] = (__bf16)v1.w;
        __syncthreads();
        bf8 afr = *(const bf8*)&Asg[w][lane][0];
        const bf8* wp = &Wf[(ch * 6) * 64 + lane];
#pragma unroll
        for (int tn = 0; tn < 6; tn++) {
            bf8 b = wp[tn * 64];
            acc[tn] = __builtin_amdgcn_mfma_f32_16x16x32_bf16(afr, b, acc[tn], 0, 0, 0);
        }
    }

    int nlo = lane & 15, q = lane >> 4;
#pragma unroll
    for (int r = 0; r < 4; r++) {
        int atom = a0 + w * 16 + q * 4 + r;
        if (atom < N_ATOMS) {
#pragma unroll
            for (int tn = 0; tn < 6; tn++) {
                int col = tn * 16 + nlo;
                float v = acc[tn][r];
                if (col < 64) ei1o[(size_t)atom * DINP1 + 256 + col] = v;
                else          sd[atom * 32 + col - 64] = v;
            }
        }
    }
    // zero pad cols 616..640
    for (int z = t; z < 64 * 24; z += 256) {
        int za = a0 + z / 24;
        if (za < N_ATOMS) ei1o[(size_t)za * DINP1 + 616 + z % 24] = 0.f;
    }
}

// ------------------------------------------------------------------
// da = (bessel(dist_angle)*switch_angle) @ W_da   -> EA x 8 fp32
// ------------------------------------------------------------------
__global__ void k_da(const float* __restrict__ dist, const float* __restrict__ sw,
                     const float* __restrict__ W, float* __restrict__ da) {
    int e = blockIdx.x * blockDim.x + threadIdx.x;
    if (e >= NEA) return;
    float d = dist[e];
    float s = sw[e];
    float rb[8];
#pragma unroll
    for (int n = 0; n < 8; n++)
        rb[n] = 0.7559289460f * __sinf((n + 1) * 0.8975979010f * d) / d * s;
    float w[8];
#pragma unroll
    for (int c = 0; c < 8; c++) {
        float acc = 0.f;
#pragma unroll
        for (int n = 0; n < 8; n++) acc += rb[n] * W[n * 8 + c];
        w[c] = acc;
    }
#pragma unroll
    for (int c = 0; c < 8; c++) da[e * 8 + c] = w[c];
}

// ------------------------------------------------------------------
// mi: per-atom segment of epay (sequential), 8 edges/iter
// ------------------------------------------------------------------
__global__ __launch_bounds__(256) void k_mi(const int* __restrict__ eoff,
                                            const float4* __restrict__ epay,
                                            const float* __restrict__ sd,
                                            float* __restrict__ mo, int stride) {
    int i = blockIdx.x;
    int beg = eoff[i], end = eoff[i + 1];
    __shared__ float rb_l[8][9];
    __shared__ float sd_l[8][33];
    int t = threadIdx.x;
    int n = t >> 5, c = t & 31;
    float acc = 0.f;
    for (int base = beg; base < end; base += 8) {
        int j = t >> 5, cc = t & 31;
        int p = base + j;
        float v = 0.f;
        if (p < end) {
            float4 ep = epay[p];
            int di = __float_as_int(ep.z);
            v = sd[di * 32 + cc];
        }
        sd_l[j][cc] = v;
        if (t < 64) {
            int jj = t >> 3, nn = t & 7;
            int pp = base + jj;
            float r = 0.f;
            if (pp < end) {
                float4 ep = epay[pp];
                float d = ep.x, s = ep.y;
                r = 0.6324555320f * __sinf((nn + 1) * 0.6283185307f * d) / d * s;
            }
            rb_l[jj][nn] = r;
        }
        __syncthreads();
#pragma unroll
        for (int j2 = 0; j2 < 8; j2++) acc += rb_l[j2][n] * sd_l[j2][c];
        __syncthreads();
    }
    mo[(size_t)i * stride + t] = acc;
}

// ------------------------------------------------------------------
// ami: per-atom segment of tpay (sequential), 8 triplets/iter
// ------------------------------------------------------------------
__global__ __launch_bounds__(64) void k_ami(const int* __restrict__ toff,
                                            const float4* __restrict__ tpay,
                                            const float* __restrict__ da,
                                            float* __restrict__ ao, int stride) {
    int i = blockIdx.x;
    int beg = toff[i], end = toff[i + 1];
    __shared__ float dij_l[8][9];
    __shared__ float xa_l[8][6];
    int t = threadIdx.x;
    int n = t >> 3, c = t & 7;
    float acc = 0.f;
    for (int base = beg; base < end; base += 8) {
        int j = t >> 3, k = t & 7;
        int p = base + j;
        float v = 0.f, th = 0.f;
        if (p < end) {
            float4 tp = tpay[p];
            int ea = __float_as_int(tp.y), eb = __float_as_int(tp.z);
            v = da[ea * 8 + k] * da[eb * 8 + k];
            th = tp.x;
        }
        dij_l[j][k] = v;
        if (k < 5) xa_l[j][k] = __cosf((float)k * th);
        __syncthreads();
        if (t < 40) {
#pragma unroll
            for (int j2 = 0; j2 < 8; j2++) acc += xa_l[j2][n] * dij_l[j2][c];
        }
        __syncthreads();
    }
    if (t < 40) ao[(size_t)i * stride + t] = acc;
}

// ------------------------------------------------------------------
// MFMA GEMM: dxi = tssr2(ei @ W + b)
// ------------------------------------------------------------------
template <int LAYER>
__global__ __launch_bounds__(256) void k_gemm(const float* __restrict__ ei,
                                              const bf8* __restrict__ Wf,
                                              const float* __restrict__ bias,
                                              const float* __restrict__ skip,
                                              float* __restrict__ out) {
    constexpr int DINP = (LAYER == 0) ? DINP0 : DINP1;
    constexpr int NCH = DINP / 32;
    __shared__ __align__(16) __bf16 Asg[2][64][8];
    int t = threadIdx.x;
    int w = t >> 6, lane = t & 63;
    int a0 = blockIdx.x * 32;

    int f  = t * 4;
    int tA = f >> 9;
    int al = (f >> 3) & 63;
    int j0 = f & 7;
    int sm = al & 15, sq = al >> 4;
    int ga = a0 + tA * 16 + sm;
    const float* arow = &ei[(size_t)ga * DINP + sq * 8 + j0];
    __bf16* adst = &Asg[0][0][0] + f;
    bool aok = (ga < N_ATOMS);

    f4 acc[2][4];
#pragma unroll
    for (int i = 0; i < 2; i++)
#pragma unroll
        for (int j = 0; j < 4; j++) {
            f4 z = {0.f, 0.f, 0.f, 0.f};
            acc[i][j] = z;
        }

    for (int ch = 0; ch < NCH; ch++) {
        float4 v = make_float4(0.f, 0.f, 0.f, 0.f);
        if (aok) v = *(const float4*)(arow + ch * 32);
        __syncthreads();
        adst[0] = (__bf16)v.x; adst[1] = (__bf16)v.y;
        adst[2] = (__bf16)v.z; adst[3] = (__bf16)v.w;
        __syncthreads();
        bf8 afr0 = *(const bf8*)&Asg[0][lane][0];
        bf8 afr1 = *(const bf8*)&Asg[1][lane][0];
        const bf8* wp = &Wf[(ch * 16 + w * 4) * 64 + lane];
#pragma unroll
        for (int tn = 0; tn < 4; tn++) {
            bf8 b = wp[tn * 64];
            acc[0][tn] = __builtin_amdgcn_mfma_f32_16x16x32_bf16(afr0, b, acc[0][tn], 0, 0, 0);
            acc[1][tn] = __builtin_amdgcn_mfma_f32_16x16x32_bf16(afr1, b, acc[1][tn], 0, 0, 0);
        }
    }

    int nlo = lane & 15, q = lane >> 4;
#pragma unroll
    for (int tA2 = 0; tA2 < 2; tA2++) {
#pragma unroll
        for (int r = 0; r < 4; r++) {
            int atom = a0 + tA2 * 16 + q * 4 + r;
            if (atom < N_ATOMS) {
#pragma unroll
                for (int tn = 0; tn < 4; tn++) {
                    int col = w * 64 + tn * 16 + nlo;
                    float vv = tssr2f(acc[tA2][tn][r] + bias[col]);
                    if (LAYER == 0) {
                        out[(size_t)atom * DINP1 + col] = vv;
                    } else {
                        out[(size_t)atom * 256 + col] = vv + skip[(size_t)atom * DINP1 + col];
                    }
                }
            }
        }
    }
}

// ------------------------------------------------------------------
extern "C" void kernel_launch(void* const* d_in, const int* in_sizes, int n_in,
                              void* d_out, int out_size, void* d_ws, size_t ws_size,
                              hipStream_t stream) {
    const int*   species     = (const int*)d_in[0];
    const int*   edge_src    = (const int*)d_in[1];
    const int*   edge_dst    = (const int*)d_in[2];
    const float* distances   = (const float*)d_in[3];
    const float* sw          = (const float*)d_in[4];
    const float* angles      = (const float*)d_in[5];
    const int*   angle_src   = (const int*)d_in[6];
    const int*   angle_dst   = (const int*)d_in[7];
    const int*   central     = (const int*)d_in[8];
    const float* dist_a      = (const float*)d_in[9];
    const float* sw_a        = (const float*)d_in[10];
    const float* table       = (const float*)d_in[11];
    const float* W_si0       = (const float*)d_in[12];
    const float* W_si1       = (const float*)d_in[13];
    const float* W_da0       = (const float*)d_in[14];
    const float* W_da1       = (const float*)d_in[15];
    const float* W_mix0      = (const float*)d_in[16];
    const float* b_mix0      = (const float*)d_in[17];
    const float* W_mix1      = (const float*)d_in[18];
    const float* b_mix1      = (const float*)d_in[19];
    float* out = (float*)d_out;

    char* p = (char*)d_ws;
    auto alloc = [&](size_t bytes) {
        char* r = p;
        p += (bytes + 255) & ~(size_t)255;
        return (void*)r;
    };
    float*  ei0  = (float*)alloc((size_t)N_ATOMS * DINP0 * 4);
    float*  ei1  = (float*)alloc((size_t)N_ATOMS * DINP1 * 4);
    float*  sd   = (float*)alloc((size_t)N_ATOMS * 32 * 4);
    float*  da   = (float*)alloc((size_t)NEA * 8 * 4);
    float4* epay = (float4*)alloc((size_t)NE * 16);
    float4* tpay = (float4*)alloc((size_t)NT * 16);
    bf8*    Wf0  = (bf8*)alloc((size_t)(DINP0 / 32) * 16 * 64 * 16);
    bf8*    Wf1  = (bf8*)alloc((size_t)(DINP1 / 32) * 16 * 64 * 16);
    bf8*    WfS1 = (bf8*)alloc((size_t)8 * 6 * 64 * 16);
    int* eoff   = (int*)alloc((size_t)(N_ATOMS + 1) * 4);
    int* toff   = (int*)alloc((size_t)(N_ATOMS + 1) * 4);
    int* ebcnt  = (int*)alloc((size_t)NBUK * 4);
    int* tbcnt  = (int*)alloc((size_t)NBUK * 4);
    int* ebkoff = (int*)alloc((size_t)(NBUK + 1) * 4);
    int* tbkoff = (int*)alloc((size_t)(NBUK + 1) * 4);
    int* gce    = (int*)alloc((size_t)NBUK * 4);
    int* gct    = (int*)alloc((size_t)NBUK * 4);
    (void)ws_size;

    // bucket staging arrays alias ei1 (written only later by k_gemm<0>)
    float4* tbuk = (float4*)ei1;
    float4* ebuk = (float4*)((char*)ei1 + (size_t)NT * 16);

    hipMemsetAsync(ebcnt, 0, (size_t)NBUK * 4, stream);
    hipMemsetAsync(tbcnt, 0, (size_t)NBUK * 4, stream);

    int nfrag0 = (DINP0 / 32) * 16 * 64;
    int nfrag1 = (DINP1 / 32) * 16 * 64;
    int nfragS = 8 * 6 * 64;
    k_wprep<<<(nfrag0 + 255) / 256, 256, 0, stream>>>(W_mix0, Wf0, DIN0, 256, 16, nfrag0);
    k_wprep<<<(nfrag1 + 255) / 256, 256, 0, stream>>>(W_mix1, Wf1, DIN1, 256, 16, nfrag1);
    k_wprep<<<(nfragS + 255) / 256, 256, 0, stream>>>(W_si1, WfS1, 256, 96, 6, nfragS);

    k_bcount<<<EBLK + (NT + 4095) / 4096, 256, 0, stream>>>(edge_src, central, ebcnt, tbcnt);
    k_scanB<<<2, 512, 0, stream>>>(ebcnt, ebkoff, gce, eoff, tbcnt, tbkoff, gct, toff);

    k_binA<true><<<(NE + 4095) / 4096, 512, 0, stream>>>(
        distances, sw, nullptr, edge_dst, edge_src, gce, ebuk, NE);
    k_binA<false><<<(NT + 4095) / 4096, 512, 0, stream>>>(
        angles, nullptr, angle_src, angle_dst, central, gct, tbuk, NT);
    k_binB<<<NBUK, 256, 0, stream>>>(ebkoff, ebuk, epay, eoff);
    k_binB<<<NBUK, 256, 0, stream>>>(tbkoff, tbuk, tpay, toff);

    int gemm_grid = (N_ATOMS + 31) / 32;

    // ---- layer 0 ----
    k_s0<<<(N_ATOMS * 120 + 255) / 256, 256, 0, stream>>>(species, table, W_si0, ei0, sd);
    k_da<<<(NEA + 255) / 256, 256, 0, stream>>>(dist_a, sw_a, W_da0, da);
    k_mi<<<N_ATOMS, 256, 0, stream>>>(eoff, epay, sd, ei0 + 80, DINP0);
    k_ami<<<N_ATOMS, 64, 0, stream>>>(toff, tpay, da, ei0 + 336, DINP0);
    k_gemm<0><<<gemm_grid, 256, 0, stream>>>(ei0, Wf0, b_mix0, nullptr, ei1);

    // ---- layer 1 ----
    k_s1<<<(N_ATOMS + 63) / 64, 256, 0, stream>>>(ei1, WfS1, ei1, sd);
    k_da<<<(NEA + 255) / 256, 256, 0, stream>>>(dist_a, sw_a, W_da1, da);
    k_mi<<<N_ATOMS, 256, 0, stream>>>(eoff, epay, sd, ei1 + 320, DINP1);
    k_ami<<<N_ATOMS, 64, 0, stream>>>(toff, tpay, da, ei1 + 576, DINP1);
    k_gemm<1><<<gemm_grid, 256, 0, stream>>>(ei1, Wf1, b_mix1, ei1, out);
}